// Round 7
// baseline (439.699 us; speedup 1.0000x reference)
//
#include <hip/hip_runtime.h>
#include <hip/hip_bf16.h>
#include <stdint.h>

// Fused causal attention block: qkv proj -> flash attention -> out proj.
// B=4 T=2048 C=1024 H=16 HD=64.  All MFMA 16x16x32 bf16, fp32 accum.
// Q is pre-scaled by 0.125*log2(e) in the qkv epilogue; softmax runs in
// base-2 domain via raw v_exp_f32. Defer-rescale (T13, THR=8).

typedef __attribute__((ext_vector_type(8))) short short8;
typedef __attribute__((ext_vector_type(4))) float f32x4;
typedef __attribute__((ext_vector_type(4))) float float4v;
typedef __attribute__((ext_vector_type(4))) unsigned short ushort4v;

#define AS1 __attribute__((address_space(1)))
#define AS3 __attribute__((address_space(3)))

#if __has_builtin(__builtin_amdgcn_exp2f)
#define EXP2(x) __builtin_amdgcn_exp2f(x)
#else
#define EXP2(x) __expf((x) * 0.69314718f)
#endif

static __device__ __forceinline__ void gload_lds16(const void* g, void* l) {
  __builtin_amdgcn_global_load_lds((const AS1 void*)g, (AS3 void*)l, 16, 0, 0);
}

// ---------------- dtype detect ----------------
__global__ void k_detect(const unsigned int* __restrict__ x, int* __restrict__ flag) {
  __shared__ int sm[256];
  int c = 0;
  for (int i = 0; i < 8; ++i) {
    unsigned int v = x[threadIdx.x * 8 + i];
    unsigned int e = (v >> 7) & 0xffu;
    if (e >= 110u && e <= 140u) c++;
  }
  sm[threadIdx.x] = c;
  __syncthreads();
  if (threadIdx.x == 0) {
    int t = 0;
    for (int i = 0; i < 256; ++i) t += sm[i];
    *flag = (t > 1024) ? 1 : 0;   // 1 = inputs are bf16, 0 = fp32
  }
}

// ---------------- fused convert: x | wqkv | wo -> contiguous bf16 ws ----------------
__global__ void k_convert3(const void* __restrict__ xs, const void* __restrict__ wqs,
                           const void* __restrict__ wos, unsigned short* __restrict__ out,
                           const int* __restrict__ flag) {
  const int f = *flag;
  const int stride = gridDim.x * blockDim.x;
  for (int v = blockIdx.x * blockDim.x + threadIdx.x; v < 3145728; v += stride) {
    const int i = v * 4;
    const void* src; int j;
    if (i < 8388608)        { src = xs;  j = i; }
    else if (i < 11534336)  { src = wqs; j = i - 8388608; }
    else                    { src = wos; j = i - 11534336; }
    ushort4v r;
    if (f) {
      r = *(const ushort4v*)((const unsigned short*)src + j);
    } else {
      float4v fv = *(const float4v*)((const float*)src + j);
#pragma unroll
      for (int e = 0; e < 4; e++) {
        __hip_bfloat16 h = __float2bfloat16(fv[e]);
        r[e] = *(unsigned short*)&h;
      }
    }
    *(ushort4v*)(out + i) = r;
  }
}

// ---------------- stage 1: QKV GEMM ----------------
__global__ __launch_bounds__(256) void k_gemm_qkv(
    const __hip_bfloat16* __restrict__ X, const __hip_bfloat16* __restrict__ W,
    __hip_bfloat16* __restrict__ qo, __hip_bfloat16* __restrict__ ko,
    __hip_bfloat16* __restrict__ vto) {
  __shared__ __align__(16) __hip_bfloat16 As[128 * 32];
  __shared__ __align__(16) __hip_bfloat16 Bs[128 * 32];
  const int tid = threadIdx.x;
  const int lane = tid & 63;
  const int wid = tid >> 6;
  const int wr = wid >> 1, wc = wid & 1;
  const int lr = lane & 15, lk = lane >> 4;
  const int m0 = blockIdx.x * 128;
  const int n0 = blockIdx.y * 128;

  const f32x4 fzero = {0.f, 0.f, 0.f, 0.f};
  f32x4 acc[4][4];
#pragma unroll
  for (int i = 0; i < 4; i++)
#pragma unroll
    for (int j = 0; j < 4; j++) acc[i][j] = fzero;

  for (int kt = 0; kt < 32; ++kt) {
    const int k0 = kt * 32;
    __syncthreads();
#pragma unroll
    for (int j = 0; j < 2; ++j) {
      const int idx = j * 256 + tid;
      const int row = idx >> 2;
      const int ce = (idx & 3) * 8;
      gload_lds16(X + (size_t)(m0 + row) * 1024 + k0 + ce,
                  (void*)(As + (size_t)(j * 256 + (tid & ~63)) * 8));
      gload_lds16(W + (size_t)(n0 + row) * 1024 + k0 + ce,
                  (void*)(Bs + (size_t)(j * 256 + (tid & ~63)) * 8));
    }
    __syncthreads();
    short8 a[4], b[4];
#pragma unroll
    for (int i = 0; i < 4; i++) a[i] = *(const short8*)(As + (wr * 64 + i * 16 + lr) * 32 + lk * 8);
#pragma unroll
    for (int i = 0; i < 4; i++) b[i] = *(const short8*)(Bs + (wc * 64 + i * 16 + lr) * 32 + lk * 8);
#pragma unroll
    for (int mf = 0; mf < 4; mf++)
#pragma unroll
      for (int nf = 0; nf < 4; nf++)
        acc[mf][nf] = __builtin_amdgcn_mfma_f32_16x16x32_bf16(a[mf], b[nf], acc[mf][nf], 0, 0, 0);
  }
#pragma unroll
  for (int mf = 0; mf < 4; mf++)
#pragma unroll
    for (int nf = 0; nf < 4; nf++)
#pragma unroll
      for (int r = 0; r < 4; r++) {
        const int row = m0 + wr * 64 + mf * 16 + lk * 4 + r;  // b*T+t
        const int col = n0 + wc * 64 + nf * 16 + lr;          // [0,3072)
        const int s = col >> 10;
        const int rem = col & 1023;
        const int h = rem >> 6, hd = rem & 63;
        const int bb = row >> 11, t = row & 2047;
        const size_t bh = (size_t)(bb * 16 + h);
        if (s == 0) {
          // pre-scale Q by 0.125 * log2(e): softmax runs in base-2 domain
          qo[(bh * 2048 + t) * 64 + hd] = __float2bfloat16(acc[mf][nf][r] * 0.18033688f);
        } else if (s == 1) {
          ko[(bh * 2048 + t) * 64 + hd] = __float2bfloat16(acc[mf][nf][r]);
        } else {
          vto[(bh * 64 + hd) * 2048 + t] = __float2bfloat16(acc[mf][nf][r]);
        }
      }
}

// ---------------- stage 2: flash attention ----------------
// 1024 blocks x 512 threads (8 waves). Q-tile 128 rows (16/wave). KV tile 64.
// LDS 48KB -> 3 blocks/CU (24 waves/CU, 3 independent barrier groups).
// bid: bh = bid&63 (same head -> same L2), p = bid>>6 (0..15) mapped to
// qtile x via balance table {g,15-g,7-g,8+g} so per-CU KV-tile sum is
// constant (68) under round-robin placement. K/V LDS double-buffered,
// gload_lds at loop top, 1 barrier/tile. XOR swizzle both-sides (rule 21).
// Base-2 softmax (raw v_exp_f32), deferred l-reduction, T13 defer-rescale.
__global__ __launch_bounds__(512, 6) void k_attn(
    const __hip_bfloat16* __restrict__ Q, const __hip_bfloat16* __restrict__ K,
    const __hip_bfloat16* __restrict__ VT, __hip_bfloat16* __restrict__ Y) {
  __shared__ __align__(16) __hip_bfloat16 Kl[2][64 * 64];
  __shared__ __align__(16) __hip_bfloat16 Vl[2][64 * 64];   // [d][key]
  __shared__ __align__(16) __hip_bfloat16 Pl[8][16 * 64];
  const int tid = threadIdx.x, lane = tid & 63, wid = tid >> 6;
  const int lr = lane & 15, lk = lane >> 4;

  const int bid = blockIdx.x;
  const int bh = bid & 63;
  const int p = bid >> 6;            // 0..15
  const int g = p & 3, j = p >> 2;
  const int x = (j == 0) ? g : (j == 1) ? 15 - g : (j == 2) ? 7 - g : 8 + g;
  const int q0 = x * 128;
  const int qb = q0 + wid * 16;      // wave owns 16 q rows
  const size_t base = (size_t)bh * 2048 * 64;

  // staging geometry: 512 chunks of 16B per 64x64 tile, 1 per thread
  const int srow = tid >> 3;                       // 0..63
  const int scol = ((tid & 7) ^ (srow & 7)) * 8;   // pre-swizzled source col
  const __hip_bfloat16* kg = K + base + scol;
  const __hip_bfloat16* vg = VT + base + (size_t)srow * 2048 + scol;

  short8 qf[2];
#pragma unroll
  for (int ks = 0; ks < 2; ks++)
    qf[ks] = *(const short8*)(Q + base + (size_t)(qb + lr) * 64 + ks * 32 + lk * 8);

  const f32x4 fzero = {0.f, 0.f, 0.f, 0.f};
  f32x4 o[4];
  float mrow[4], lrow[4];
#pragma unroll
  for (int nf = 0; nf < 4; nf++) o[nf] = fzero;
#pragma unroll
  for (int r = 0; r < 4; r++) { mrow[r] = -1e30f; lrow[r] = 0.f; }

  const int nkv = 2 * x + 2;
  // prologue: stage tile 0 into buf 0
  gload_lds16(kg + (size_t)srow * 64, (void*)(&Kl[0][0] + (tid & ~63) * 8));
  gload_lds16(vg, (void*)(&Vl[0][0] + (tid & ~63) * 8));
  __syncthreads();   // drains vmcnt+lgkmcnt, joins waves

  int cur = 0;
  for (int kt = 0; kt < nkv; ++kt) {
    const int k0 = kt * 64;
    // issue next tile's loads first (latency hides under compute)
    if (kt + 1 < nkv) {
      const int kn = (kt + 1) * 64;
      gload_lds16(kg + (size_t)(kn + srow) * 64, (void*)(&Kl[cur ^ 1][0] + (tid & ~63) * 8));
      gload_lds16(vg + kn, (void*)(&Vl[cur ^ 1][0] + (tid & ~63) * 8));
    }

    if (k0 <= qb + 15) {   // wave-uniform: skip fully-masked tiles
      f32x4 s[4];
#pragma unroll
      for (int nf = 0; nf < 4; nf++) s[nf] = fzero;
      __builtin_amdgcn_s_setprio(1);
#pragma unroll
      for (int ks = 0; ks < 2; ks++) {
        short8 kb[4];
#pragma unroll
        for (int nf = 0; nf < 4; nf++) {
          const int r = nf * 16 + lr;
          kb[nf] = *(const short8*)(&Kl[cur][0] + r * 64 + (((ks * 4 + lk) ^ (r & 7)) * 8));
        }
#pragma unroll
        for (int nf = 0; nf < 4; nf++)
          s[nf] = __builtin_amdgcn_mfma_f32_16x16x32_bf16(qf[ks], kb[nf], s[nf], 0, 0, 0);
      }
      __builtin_amdgcn_s_setprio(0);

      const bool needmask = (k0 + 63 > qb);   // wave-uniform: diagonal tile?

      // online softmax, base-2 domain (acc layout: row = lk*4+r, col = lr)
#pragma unroll
      for (int r = 0; r < 4; r++) {
        const int rowg = qb + lk * 4 + r;
        const int pr = lk * 4 + r;
        float mx = -1e30f;
        if (needmask) {
#pragma unroll
          for (int nf = 0; nf < 4; nf++) {
            float sv = s[nf][r];
            if (k0 + nf * 16 + lr > rowg) sv = -1e30f;
            s[nf][r] = sv;
            mx = fmaxf(mx, sv);
          }
        } else {
#pragma unroll
          for (int nf = 0; nf < 4; nf++) mx = fmaxf(mx, s[nf][r]);
        }
#pragma unroll
        for (int d = 1; d < 16; d <<= 1) mx = fmaxf(mx, __shfl_xor(mx, d, 64));
        const float mold = mrow[r];
        float rs = 0.f;
        if (__all(mx - mold <= 8.f)) {
          // T13 defer: keep old max, skip rescale (P bounded by 2^8)
#pragma unroll
          for (int nf = 0; nf < 4; nf++) {
            const float pv = EXP2(s[nf][r] - mold);
            rs += pv;
            const int ce = nf * 16 + lr;
            Pl[wid][pr * 64 + (ce ^ ((pr & 7) << 3))] = __float2bfloat16(pv);
          }
          lrow[r] += rs;
        } else {
          const float mnew = fmaxf(mold, mx);
          const float alpha = EXP2(mold - mnew);
#pragma unroll
          for (int nf = 0; nf < 4; nf++) {
            const float pv = EXP2(s[nf][r] - mnew);
            rs += pv;
            const int ce = nf * 16 + lr;
            Pl[wid][pr * 64 + (ce ^ ((pr & 7) << 3))] = __float2bfloat16(pv);
          }
          lrow[r] = lrow[r] * alpha + rs;
          mrow[r] = mnew;
#pragma unroll
          for (int nf = 0; nf < 4; nf++) o[nf][r] *= alpha;
        }
      }

      asm volatile("s_waitcnt lgkmcnt(0)" ::: "memory");
      __builtin_amdgcn_sched_barrier(0);

      // PV: A = P (rows = q, lane row = lr), B = V^T rows d (k contiguous)
      __builtin_amdgcn_s_setprio(1);
#pragma unroll
      for (int ks = 0; ks < 2; ks++) {
        short8 pa, vb[4];
        pa = *(const short8*)(&Pl[wid][0] + lr * 64 + (((ks * 4 + lk) ^ (lr & 7)) * 8));
#pragma unroll
        for (int nf = 0; nf < 4; nf++) {
          const int d = nf * 16 + lr;
          vb[nf] = *(const short8*)(&Vl[cur][0] + d * 64 + (((ks * 4 + lk) ^ (d & 7)) * 8));
        }
#pragma unroll
        for (int nf = 0; nf < 4; nf++)
          o[nf] = __builtin_amdgcn_mfma_f32_16x16x32_bf16(pa, vb[nf], o[nf], 0, 0, 0);
      }
      __builtin_amdgcn_s_setprio(0);
    }

    // single barrier per tile: drains own gloads (issued pre-compute ->
    // latency hidden) and joins waves before buffer flip.
    __syncthreads();
    cur ^= 1;
  }

  const int b = bh >> 4, h = bh & 15;
#pragma unroll
  for (int r = 0; r < 4; r++) {
    // deferred l reduction: sum per-lane partials across the 16-lane group
    float ls = lrow[r];
#pragma unroll
    for (int d = 1; d < 16; d <<= 1) ls += __shfl_xor(ls, d, 64);
    const float inv = 1.f / ls;
    const int t = qb + lk * 4 + r;
#pragma unroll
    for (int nf = 0; nf < 4; nf++)
      Y[((size_t)b * 2048 + t) * 1024 + h * 64 + nf * 16 + lr] =
          __float2bfloat16(o[nf][r] * inv);
  }
}

// ---------------- stage 3: output GEMM ----------------
__global__ __launch_bounds__(256) void k_gemm_out(
    const __hip_bfloat16* __restrict__ X, const __hip_bfloat16* __restrict__ W,
    void* __restrict__ out, const int* __restrict__ flag) {
  __shared__ __align__(16) __hip_bfloat16 As[128 * 32];
  __shared__ __align__(16) __hip_bfloat16 Bs[128 * 32];
  const int tid = threadIdx.x;
  const int lane = tid & 63;
  const int wid = tid >> 6;
  const int wr = wid >> 1, wc = wid & 1;
  const int lr = lane & 15, lk = lane >> 4;
  const int m0 = blockIdx.x * 128;
  const int n0 = blockIdx.y * 128;

  const f32x4 fzero = {0.f, 0.f, 0.f, 0.f};
  f32x4 acc[4][4];
#pragma unroll
  for (int i = 0; i < 4; i++)
#pragma unroll
    for (int j = 0; j < 4; j++) acc[i][j] = fzero;

  for (int kt = 0; kt < 32; ++kt) {
    const int k0 = kt * 32;
    __syncthreads();
#pragma unroll
    for (int j = 0; j < 2; ++j) {
      const int idx = j * 256 + tid;
      const int row = idx >> 2;
      const int ce = (idx & 3) * 8;
      gload_lds16(X + (size_t)(m0 + row) * 1024 + k0 + ce,
                  (void*)(As + (size_t)(j * 256 + (tid & ~63)) * 8));
      gload_lds16(W + (size_t)(n0 + row) * 1024 + k0 + ce,
                  (void*)(Bs + (size_t)(j * 256 + (tid & ~63)) * 8));
    }
    __syncthreads();
    short8 a[4], b[4];
#pragma unroll
    for (int i = 0; i < 4; i++) a[i] = *(const short8*)(As + (wr * 64 + i * 16 + lr) * 32 + lk * 8);
#pragma unroll
    for (int i = 0; i < 4; i++) b[i] = *(const short8*)(Bs + (wc * 64 + i * 16 + lr) * 32 + lk * 8);
#pragma unroll
    for (int mf = 0; mf < 4; mf++)
#pragma unroll
      for (int nf = 0; nf < 4; nf++)
        acc[mf][nf] = __builtin_amdgcn_mfma_f32_16x16x32_bf16(a[mf], b[nf], acc[mf][nf], 0, 0, 0);
  }
  const int f = *flag;
#pragma unroll
  for (int mf = 0; mf < 4; mf++)
#pragma unroll
    for (int nf = 0; nf < 4; nf++)
#pragma unroll
      for (int r = 0; r < 4; r++) {
        const int row = m0 + wr * 64 + mf * 16 + lk * 4 + r;
        const int col = n0 + wc * 64 + nf * 16 + lr;
        const size_t oi = (size_t)row * 1024 + col;
        if (f) ((__hip_bfloat16*)out)[oi] = __float2bfloat16(acc[mf][nf][r]);
        else   ((float*)out)[oi] = acc[mf][nf][r];
      }
}

// ---------------- launch ----------------
extern "C" void kernel_launch(void* const* d_in, const int* in_sizes, int n_in,
                              void* d_out, int out_size, void* d_ws, size_t ws_size,
                              hipStream_t stream) {
  const void* x = d_in[0];     // [4,2048,1024]
  const void* wqkv = d_in[1];  // [3072,1024]
  const void* wo = d_in[2];    // [1024,1024]

  char* ws = (char*)d_ws;
  int* flag = (int*)ws;
  __hip_bfloat16* xb    = (__hip_bfloat16*)(ws + 256);
  __hip_bfloat16* wqkvb = xb + 8388608;
  __hip_bfloat16* wob   = wqkvb + 3145728;
  __hip_bfloat16* qws   = wob + 1048576;
  __hip_bfloat16* kws   = qws + 8388608;   // 64*2048*64
  __hip_bfloat16* vtws  = kws + 8388608;
  __hip_bfloat16* yws   = xb;              // alias: xb dead after QKV GEMM
  // peak ws use: ~72 MB

  k_detect<<<1, 256, 0, stream>>>((const unsigned int*)x, flag);
  k_convert3<<<2048, 256, 0, stream>>>(x, wqkv, wo, (unsigned short*)xb, flag);

  dim3 g1(64, 24);
  k_gemm_qkv<<<g1, 256, 0, stream>>>(xb, wqkvb, qws, kws, vtws);

  k_attn<<<1024, 512, 0, stream>>>(qws, kws, vtws, yws);

  dim3 g3(64, 8);
  k_gemm_out<<<g3, 256, 0, stream>>>(yws, wob, d_out, flag);
}

// Round 8
// 278.435 us; speedup vs baseline: 1.5792x; 1.5792x over previous
//
#include <hip/hip_runtime.h>
#include <hip/hip_bf16.h>
#include <stdint.h>

// Fused causal attention block: qkv proj -> flash attention -> out proj.
// B=4 T=2048 C=1024 H=16 HD=64.  All MFMA 16x16x32 bf16, fp32 accum.
// Q is pre-scaled by 0.125*log2(e) in the qkv epilogue; softmax runs in
// base-2 domain via raw v_exp_f32. Defer-rescale (T13, THR=8).

typedef __attribute__((ext_vector_type(8))) short short8;
typedef __attribute__((ext_vector_type(4))) float f32x4;
typedef __attribute__((ext_vector_type(4))) float float4v;
typedef __attribute__((ext_vector_type(4))) unsigned short ushort4v;

#define AS1 __attribute__((address_space(1)))
#define AS3 __attribute__((address_space(3)))

#if __has_builtin(__builtin_amdgcn_exp2f)
#define EXP2(x) __builtin_amdgcn_exp2f(x)
#else
#define EXP2(x) __expf((x) * 0.69314718f)
#endif

static __device__ __forceinline__ void gload_lds16(const void* g, void* l) {
  __builtin_amdgcn_global_load_lds((const AS1 void*)g, (AS3 void*)l, 16, 0, 0);
}

// ---------------- dtype detect ----------------
__global__ void k_detect(const unsigned int* __restrict__ x, int* __restrict__ flag) {
  __shared__ int sm[256];
  int c = 0;
  for (int i = 0; i < 8; ++i) {
    unsigned int v = x[threadIdx.x * 8 + i];
    unsigned int e = (v >> 7) & 0xffu;
    if (e >= 110u && e <= 140u) c++;
  }
  sm[threadIdx.x] = c;
  __syncthreads();
  if (threadIdx.x == 0) {
    int t = 0;
    for (int i = 0; i < 256; ++i) t += sm[i];
    *flag = (t > 1024) ? 1 : 0;   // 1 = inputs are bf16, 0 = fp32
  }
}

// ---------------- fused convert: x | wqkv | wo -> contiguous bf16 ws ----------------
__global__ void k_convert3(const void* __restrict__ xs, const void* __restrict__ wqs,
                           const void* __restrict__ wos, unsigned short* __restrict__ out,
                           const int* __restrict__ flag) {
  const int f = *flag;
  const int stride = gridDim.x * blockDim.x;
  for (int v = blockIdx.x * blockDim.x + threadIdx.x; v < 3145728; v += stride) {
    const int i = v * 4;
    const void* src; int j;
    if (i < 8388608)        { src = xs;  j = i; }
    else if (i < 11534336)  { src = wqs; j = i - 8388608; }
    else                    { src = wos; j = i - 11534336; }
    ushort4v r;
    if (f) {
      r = *(const ushort4v*)((const unsigned short*)src + j);
    } else {
      float4v fv = *(const float4v*)((const float*)src + j);
#pragma unroll
      for (int e = 0; e < 4; e++) {
        __hip_bfloat16 h = __float2bfloat16(fv[e]);
        r[e] = *(unsigned short*)&h;
      }
    }
    *(ushort4v*)(out + i) = r;
  }
}

// ---------------- stage 1: QKV GEMM ----------------
__global__ __launch_bounds__(256) void k_gemm_qkv(
    const __hip_bfloat16* __restrict__ X, const __hip_bfloat16* __restrict__ W,
    __hip_bfloat16* __restrict__ qo, __hip_bfloat16* __restrict__ ko,
    __hip_bfloat16* __restrict__ vto) {
  __shared__ __align__(16) __hip_bfloat16 As[128 * 32];
  __shared__ __align__(16) __hip_bfloat16 Bs[128 * 32];
  const int tid = threadIdx.x;
  const int lane = tid & 63;
  const int wid = tid >> 6;
  const int wr = wid >> 1, wc = wid & 1;
  const int lr = lane & 15, lk = lane >> 4;
  const int m0 = blockIdx.x * 128;
  const int n0 = blockIdx.y * 128;

  const f32x4 fzero = {0.f, 0.f, 0.f, 0.f};
  f32x4 acc[4][4];
#pragma unroll
  for (int i = 0; i < 4; i++)
#pragma unroll
    for (int j = 0; j < 4; j++) acc[i][j] = fzero;

  for (int kt = 0; kt < 32; ++kt) {
    const int k0 = kt * 32;
    __syncthreads();
#pragma unroll
    for (int j = 0; j < 2; ++j) {
      const int idx = j * 256 + tid;
      const int row = idx >> 2;
      const int ce = (idx & 3) * 8;
      gload_lds16(X + (size_t)(m0 + row) * 1024 + k0 + ce,
                  (void*)(As + (size_t)(j * 256 + (tid & ~63)) * 8));
      gload_lds16(W + (size_t)(n0 + row) * 1024 + k0 + ce,
                  (void*)(Bs + (size_t)(j * 256 + (tid & ~63)) * 8));
    }
    __syncthreads();
    short8 a[4], b[4];
#pragma unroll
    for (int i = 0; i < 4; i++) a[i] = *(const short8*)(As + (wr * 64 + i * 16 + lr) * 32 + lk * 8);
#pragma unroll
    for (int i = 0; i < 4; i++) b[i] = *(const short8*)(Bs + (wc * 64 + i * 16 + lr) * 32 + lk * 8);
#pragma unroll
    for (int mf = 0; mf < 4; mf++)
#pragma unroll
      for (int nf = 0; nf < 4; nf++)
        acc[mf][nf] = __builtin_amdgcn_mfma_f32_16x16x32_bf16(a[mf], b[nf], acc[mf][nf], 0, 0, 0);
  }
#pragma unroll
  for (int mf = 0; mf < 4; mf++)
#pragma unroll
    for (int nf = 0; nf < 4; nf++)
#pragma unroll
      for (int r = 0; r < 4; r++) {
        const int row = m0 + wr * 64 + mf * 16 + lk * 4 + r;  // b*T+t
        const int col = n0 + wc * 64 + nf * 16 + lr;          // [0,3072)
        const int s = col >> 10;
        const int rem = col & 1023;
        const int h = rem >> 6, hd = rem & 63;
        const int bb = row >> 11, t = row & 2047;
        const size_t bh = (size_t)(bb * 16 + h);
        if (s == 0) {
          // pre-scale Q by 0.125 * log2(e): softmax runs in base-2 domain
          qo[(bh * 2048 + t) * 64 + hd] = __float2bfloat16(acc[mf][nf][r] * 0.18033688f);
        } else if (s == 1) {
          ko[(bh * 2048 + t) * 64 + hd] = __float2bfloat16(acc[mf][nf][r]);
        } else {
          vto[(bh * 64 + hd) * 2048 + t] = __float2bfloat16(acc[mf][nf][r]);
        }
      }
}

// ---------------- stage 2: flash attention ----------------
// 512 persistent blocks x 512 threads (8 waves). Each block runs TWO
// 128-row q-tiles sequentially: x = 15-p then x = p  (p = bid>>6, 0..7).
// Per-block work = 2(15-p)+2 + 2p+2 = 34 KV-tiles for EVERY block ->
// both co-resident blocks per CU carry equal work: sustained 16 waves/CU,
// no concurrency collapse (round-6 flaw), no spill (round-7 flaw: forced
// launch_bounds min-waves; now natural VGPR).
// Wave owns 16 q rows. KV tile 64, LDS dbuf flows across the phase
// boundary. XOR swizzle both-sides (rule 21). Base-2 softmax, deferred
// l-reduction, T13 defer-rescale.
__global__ __launch_bounds__(512) void k_attn(
    const __hip_bfloat16* __restrict__ Q, const __hip_bfloat16* __restrict__ K,
    const __hip_bfloat16* __restrict__ VT, __hip_bfloat16* __restrict__ Y) {
  __shared__ __align__(16) __hip_bfloat16 Kl[2][64 * 64];
  __shared__ __align__(16) __hip_bfloat16 Vl[2][64 * 64];   // [d][key]
  __shared__ __align__(16) __hip_bfloat16 Pl[8][16 * 64];
  const int tid = threadIdx.x, lane = tid & 63, wid = tid >> 6;
  const int lr = lane & 15, lk = lane >> 4;

  const int bid = blockIdx.x;
  const int bh = bid & 63;
  const int p = bid >> 6;            // 0..7
  const size_t base = (size_t)bh * 2048 * 64;
  const int b = bh >> 4, h = bh & 15;

  // staging geometry: 512 chunks of 16B per 64x64 tile, 1 per thread
  const int srow = tid >> 3;                       // 0..63
  const int scol = ((tid & 7) ^ (srow & 7)) * 8;   // pre-swizzled source col
  const __hip_bfloat16* kg = K + base + scol;
  const __hip_bfloat16* vg = VT + base + (size_t)srow * 2048 + scol;

  const f32x4 fzero = {0.f, 0.f, 0.f, 0.f};
  int cur = 0;

  for (int ph = 0; ph < 2; ++ph) {
    const int x = ph ? p : 15 - p;   // big tile first; total 34 for all blocks
    const int q0 = x * 128;
    const int qb = q0 + wid * 16;    // wave owns 16 q rows

    short8 qf[2];
#pragma unroll
    for (int ks = 0; ks < 2; ks++)
      qf[ks] = *(const short8*)(Q + base + (size_t)(qb + lr) * 64 + ks * 32 + lk * 8);

    f32x4 o[4];
    float mrow[4], lrow[4];
#pragma unroll
    for (int nf = 0; nf < 4; nf++) o[nf] = fzero;
#pragma unroll
    for (int r = 0; r < 4; r++) { mrow[r] = -1e30f; lrow[r] = 0.f; }

    const int nkv = 2 * x + 2;
    // prologue: stage tile 0 into buf cur
    gload_lds16(kg + (size_t)srow * 64, (void*)(&Kl[cur][0] + (tid & ~63) * 8));
    gload_lds16(vg, (void*)(&Vl[cur][0] + (tid & ~63) * 8));
    __syncthreads();   // drains vmcnt+lgkmcnt, joins waves

    for (int kt = 0; kt < nkv; ++kt) {
      const int k0 = kt * 64;
      // issue next tile's loads first (latency hides under compute)
      if (kt + 1 < nkv) {
        const int kn = (kt + 1) * 64;
        gload_lds16(kg + (size_t)(kn + srow) * 64, (void*)(&Kl[cur ^ 1][0] + (tid & ~63) * 8));
        gload_lds16(vg + kn, (void*)(&Vl[cur ^ 1][0] + (tid & ~63) * 8));
      }

      if (k0 <= qb + 15) {   // wave-uniform: skip fully-masked tiles
        f32x4 s[4];
#pragma unroll
        for (int nf = 0; nf < 4; nf++) s[nf] = fzero;
        __builtin_amdgcn_s_setprio(1);
#pragma unroll
        for (int ks = 0; ks < 2; ks++) {
          short8 kb[4];
#pragma unroll
          for (int nf = 0; nf < 4; nf++) {
            const int r = nf * 16 + lr;
            kb[nf] = *(const short8*)(&Kl[cur][0] + r * 64 + (((ks * 4 + lk) ^ (r & 7)) * 8));
          }
#pragma unroll
          for (int nf = 0; nf < 4; nf++)
            s[nf] = __builtin_amdgcn_mfma_f32_16x16x32_bf16(qf[ks], kb[nf], s[nf], 0, 0, 0);
        }
        __builtin_amdgcn_s_setprio(0);

        const bool needmask = (k0 + 63 > qb);   // wave-uniform: diagonal tile?

        // online softmax, base-2 domain (acc layout: row = lk*4+r, col = lr)
#pragma unroll
        for (int r = 0; r < 4; r++) {
          const int rowg = qb + lk * 4 + r;
          const int pr = lk * 4 + r;
          float mx = -1e30f;
          if (needmask) {
#pragma unroll
            for (int nf = 0; nf < 4; nf++) {
              float sv = s[nf][r];
              if (k0 + nf * 16 + lr > rowg) sv = -1e30f;
              s[nf][r] = sv;
              mx = fmaxf(mx, sv);
            }
          } else {
#pragma unroll
            for (int nf = 0; nf < 4; nf++) mx = fmaxf(mx, s[nf][r]);
          }
#pragma unroll
          for (int d = 1; d < 16; d <<= 1) mx = fmaxf(mx, __shfl_xor(mx, d, 64));
          const float mold = mrow[r];
          float rs = 0.f;
          if (__all(mx - mold <= 8.f)) {
            // T13 defer: keep old max, skip rescale (P bounded by 2^8)
#pragma unroll
            for (int nf = 0; nf < 4; nf++) {
              const float pv = EXP2(s[nf][r] - mold);
              rs += pv;
              const int ce = nf * 16 + lr;
              Pl[wid][pr * 64 + (ce ^ ((pr & 7) << 3))] = __float2bfloat16(pv);
            }
            lrow[r] += rs;
          } else {
            const float mnew = fmaxf(mold, mx);
            const float alpha = EXP2(mold - mnew);
#pragma unroll
            for (int nf = 0; nf < 4; nf++) {
              const float pv = EXP2(s[nf][r] - mnew);
              rs += pv;
              const int ce = nf * 16 + lr;
              Pl[wid][pr * 64 + (ce ^ ((pr & 7) << 3))] = __float2bfloat16(pv);
            }
            lrow[r] = lrow[r] * alpha + rs;
            mrow[r] = mnew;
#pragma unroll
            for (int nf = 0; nf < 4; nf++) o[nf][r] *= alpha;
          }
        }

        asm volatile("s_waitcnt lgkmcnt(0)" ::: "memory");
        __builtin_amdgcn_sched_barrier(0);

        // PV: A = P (rows = q, lane row = lr), B = V^T rows d (k contiguous)
        __builtin_amdgcn_s_setprio(1);
#pragma unroll
        for (int ks = 0; ks < 2; ks++) {
          short8 pa, vb[4];
          pa = *(const short8*)(&Pl[wid][0] + lr * 64 + (((ks * 4 + lk) ^ (lr & 7)) * 8));
#pragma unroll
          for (int nf = 0; nf < 4; nf++) {
            const int d = nf * 16 + lr;
            vb[nf] = *(const short8*)(&Vl[cur][0] + d * 64 + (((ks * 4 + lk) ^ (d & 7)) * 8));
          }
#pragma unroll
          for (int nf = 0; nf < 4; nf++)
            o[nf] = __builtin_amdgcn_mfma_f32_16x16x32_bf16(pa, vb[nf], o[nf], 0, 0, 0);
        }
        __builtin_amdgcn_s_setprio(0);
      }

      // single barrier per tile: drains own gloads (issued pre-compute ->
      // latency hidden) and joins waves before buffer flip.
      __syncthreads();
      cur ^= 1;
    }

    // phase epilogue (registers only -> no LDS hazard with next prologue)
#pragma unroll
    for (int r = 0; r < 4; r++) {
      // deferred l reduction: sum per-lane partials across the 16-lane group
      float ls = lrow[r];
#pragma unroll
      for (int d = 1; d < 16; d <<= 1) ls += __shfl_xor(ls, d, 64);
      const float inv = 1.f / ls;
      const int t = qb + lk * 4 + r;
#pragma unroll
      for (int nf = 0; nf < 4; nf++)
        Y[((size_t)b * 2048 + t) * 1024 + h * 64 + nf * 16 + lr] =
            __float2bfloat16(o[nf][r] * inv);
    }
  }
}

// ---------------- stage 3: output GEMM ----------------
__global__ __launch_bounds__(256) void k_gemm_out(
    const __hip_bfloat16* __restrict__ X, const __hip_bfloat16* __restrict__ W,
    void* __restrict__ out, const int* __restrict__ flag) {
  __shared__ __align__(16) __hip_bfloat16 As[128 * 32];
  __shared__ __align__(16) __hip_bfloat16 Bs[128 * 32];
  const int tid = threadIdx.x;
  const int lane = tid & 63;
  const int wid = tid >> 6;
  const int wr = wid >> 1, wc = wid & 1;
  const int lr = lane & 15, lk = lane >> 4;
  const int m0 = blockIdx.x * 128;
  const int n0 = blockIdx.y * 128;

  const f32x4 fzero = {0.f, 0.f, 0.f, 0.f};
  f32x4 acc[4][4];
#pragma unroll
  for (int i = 0; i < 4; i++)
#pragma unroll
    for (int j = 0; j < 4; j++) acc[i][j] = fzero;

  for (int kt = 0; kt < 32; ++kt) {
    const int k0 = kt * 32;
    __syncthreads();
#pragma unroll
    for (int j = 0; j < 2; ++j) {
      const int idx = j * 256 + tid;
      const int row = idx >> 2;
      const int ce = (idx & 3) * 8;
      gload_lds16(X + (size_t)(m0 + row) * 1024 + k0 + ce,
                  (void*)(As + (size_t)(j * 256 + (tid & ~63)) * 8));
      gload_lds16(W + (size_t)(n0 + row) * 1024 + k0 + ce,
                  (void*)(Bs + (size_t)(j * 256 + (tid & ~63)) * 8));
    }
    __syncthreads();
    short8 a[4], b[4];
#pragma unroll
    for (int i = 0; i < 4; i++) a[i] = *(const short8*)(As + (wr * 64 + i * 16 + lr) * 32 + lk * 8);
#pragma unroll
    for (int i = 0; i < 4; i++) b[i] = *(const short8*)(Bs + (wc * 64 + i * 16 + lr) * 32 + lk * 8);
#pragma unroll
    for (int mf = 0; mf < 4; mf++)
#pragma unroll
      for (int nf = 0; nf < 4; nf++)
        acc[mf][nf] = __builtin_amdgcn_mfma_f32_16x16x32_bf16(a[mf], b[nf], acc[mf][nf], 0, 0, 0);
  }
  const int f = *flag;
#pragma unroll
  for (int mf = 0; mf < 4; mf++)
#pragma unroll
    for (int nf = 0; nf < 4; nf++)
#pragma unroll
      for (int r = 0; r < 4; r++) {
        const int row = m0 + wr * 64 + mf * 16 + lk * 4 + r;
        const int col = n0 + wc * 64 + nf * 16 + lr;
        const size_t oi = (size_t)row * 1024 + col;
        if (f) ((__hip_bfloat16*)out)[oi] = __float2bfloat16(acc[mf][nf][r]);
        else   ((float*)out)[oi] = acc[mf][nf][r];
      }
}

// ---------------- launch ----------------
extern "C" void kernel_launch(void* const* d_in, const int* in_sizes, int n_in,
                              void* d_out, int out_size, void* d_ws, size_t ws_size,
                              hipStream_t stream) {
  const void* x = d_in[0];     // [4,2048,1024]
  const void* wqkv = d_in[1];  // [3072,1024]
  const void* wo = d_in[2];    // [1024,1024]

  char* ws = (char*)d_ws;
  int* flag = (int*)ws;
  __hip_bfloat16* xb    = (__hip_bfloat16*)(ws + 256);
  __hip_bfloat16* wqkvb = xb + 8388608;
  __hip_bfloat16* wob   = wqkvb + 3145728;
  __hip_bfloat16* qws   = wob + 1048576;
  __hip_bfloat16* kws   = qws + 8388608;   // 64*2048*64
  __hip_bfloat16* vtws  = kws + 8388608;
  __hip_bfloat16* yws   = xb;              // alias: xb dead after QKV GEMM
  // peak ws use: ~72 MB

  k_detect<<<1, 256, 0, stream>>>((const unsigned int*)x, flag);
  k_convert3<<<2048, 256, 0, stream>>>(x, wqkv, wo, (unsigned short*)xb, flag);

  dim3 g1(64, 24);
  k_gemm_qkv<<<g1, 256, 0, stream>>>(xb, wqkvb, qws, kws, vtws);

  k_attn<<<512, 512, 0, stream>>>(qws, kws, vtws, yws);

  dim3 g3(64, 8);
  k_gemm_out<<<g3, 256, 0, stream>>>(yws, wob, d_out, flag);
}

// Round 9
// 249.839 us; speedup vs baseline: 1.7599x; 1.1145x over previous
//
#include <hip/hip_runtime.h>
#include <hip/hip_bf16.h>
#include <stdint.h>

// Fused causal attention block: qkv proj -> flash attention -> out proj.
// B=4 T=2048 C=1024 H=16 HD=64.  All MFMA 16x16x32 bf16, fp32 accum.
// Q pre-scaled by 0.125*log2(e); base-2 softmax via raw v_exp_f32; T13.
// attn: 3-buffer KV pipeline with counted vmcnt (T4) - no vmcnt(0) drain.

typedef __attribute__((ext_vector_type(8))) short short8;
typedef __attribute__((ext_vector_type(4))) float f32x4;
typedef __attribute__((ext_vector_type(4))) float float4v;
typedef __attribute__((ext_vector_type(4))) unsigned short ushort4v;

#define AS1 __attribute__((address_space(1)))
#define AS3 __attribute__((address_space(3)))

#if __has_builtin(__builtin_amdgcn_exp2f)
#define EXP2(x) __builtin_amdgcn_exp2f(x)
#else
#define EXP2(x) __expf((x) * 0.69314718f)
#endif

static __device__ __forceinline__ void gload_lds16(const void* g, void* l) {
  __builtin_amdgcn_global_load_lds((const AS1 void*)g, (AS3 void*)l, 16, 0, 0);
}

// ---------------- dtype detect ----------------
__global__ void k_detect(const unsigned int* __restrict__ x, int* __restrict__ flag) {
  __shared__ int sm[256];
  int c = 0;
  for (int i = 0; i < 8; ++i) {
    unsigned int v = x[threadIdx.x * 8 + i];
    unsigned int e = (v >> 7) & 0xffu;
    if (e >= 110u && e <= 140u) c++;
  }
  sm[threadIdx.x] = c;
  __syncthreads();
  if (threadIdx.x == 0) {
    int t = 0;
    for (int i = 0; i < 256; ++i) t += sm[i];
    *flag = (t > 1024) ? 1 : 0;   // 1 = inputs are bf16, 0 = fp32
  }
}

// ---------------- fused convert: x | wqkv | wo -> contiguous bf16 ws ----------------
__global__ void k_convert3(const void* __restrict__ xs, const void* __restrict__ wqs,
                           const void* __restrict__ wos, unsigned short* __restrict__ out,
                           const int* __restrict__ flag) {
  const int f = *flag;
  const int stride = gridDim.x * blockDim.x;
  for (int v = blockIdx.x * blockDim.x + threadIdx.x; v < 3145728; v += stride) {
    const int i = v * 4;
    const void* src; int j;
    if (i < 8388608)        { src = xs;  j = i; }
    else if (i < 11534336)  { src = wqs; j = i - 8388608; }
    else                    { src = wos; j = i - 11534336; }
    ushort4v r;
    if (f) {
      r = *(const ushort4v*)((const unsigned short*)src + j);
    } else {
      float4v fv = *(const float4v*)((const float*)src + j);
#pragma unroll
      for (int e = 0; e < 4; e++) {
        __hip_bfloat16 h = __float2bfloat16(fv[e]);
        r[e] = *(unsigned short*)&h;
      }
    }
    *(ushort4v*)(out + i) = r;
  }
}

// ---------------- stage 1: QKV GEMM ----------------
__global__ __launch_bounds__(256) void k_gemm_qkv(
    const __hip_bfloat16* __restrict__ X, const __hip_bfloat16* __restrict__ W,
    __hip_bfloat16* __restrict__ qo, __hip_bfloat16* __restrict__ ko,
    __hip_bfloat16* __restrict__ vto) {
  __shared__ __align__(16) __hip_bfloat16 As[128 * 32];
  __shared__ __align__(16) __hip_bfloat16 Bs[128 * 32];
  const int tid = threadIdx.x;
  const int lane = tid & 63;
  const int wid = tid >> 6;
  const int wr = wid >> 1, wc = wid & 1;
  const int lr = lane & 15, lk = lane >> 4;
  const int m0 = blockIdx.x * 128;
  const int n0 = blockIdx.y * 128;

  const f32x4 fzero = {0.f, 0.f, 0.f, 0.f};
  f32x4 acc[4][4];
#pragma unroll
  for (int i = 0; i < 4; i++)
#pragma unroll
    for (int j = 0; j < 4; j++) acc[i][j] = fzero;

  for (int kt = 0; kt < 32; ++kt) {
    const int k0 = kt * 32;
    __syncthreads();
#pragma unroll
    for (int j = 0; j < 2; ++j) {
      const int idx = j * 256 + tid;
      const int row = idx >> 2;
      const int ce = (idx & 3) * 8;
      gload_lds16(X + (size_t)(m0 + row) * 1024 + k0 + ce,
                  (void*)(As + (size_t)(j * 256 + (tid & ~63)) * 8));
      gload_lds16(W + (size_t)(n0 + row) * 1024 + k0 + ce,
                  (void*)(Bs + (size_t)(j * 256 + (tid & ~63)) * 8));
    }
    __syncthreads();
    short8 a[4], b[4];
#pragma unroll
    for (int i = 0; i < 4; i++) a[i] = *(const short8*)(As + (wr * 64 + i * 16 + lr) * 32 + lk * 8);
#pragma unroll
    for (int i = 0; i < 4; i++) b[i] = *(const short8*)(Bs + (wc * 64 + i * 16 + lr) * 32 + lk * 8);
#pragma unroll
    for (int mf = 0; mf < 4; mf++)
#pragma unroll
      for (int nf = 0; nf < 4; nf++)
        acc[mf][nf] = __builtin_amdgcn_mfma_f32_16x16x32_bf16(a[mf], b[nf], acc[mf][nf], 0, 0, 0);
  }
#pragma unroll
  for (int mf = 0; mf < 4; mf++)
#pragma unroll
    for (int nf = 0; nf < 4; nf++)
#pragma unroll
      for (int r = 0; r < 4; r++) {
        const int row = m0 + wr * 64 + mf * 16 + lk * 4 + r;  // b*T+t
        const int col = n0 + wc * 64 + nf * 16 + lr;          // [0,3072)
        const int s = col >> 10;
        const int rem = col & 1023;
        const int h = rem >> 6, hd = rem & 63;
        const int bb = row >> 11, t = row & 2047;
        const size_t bh = (size_t)(bb * 16 + h);
        if (s == 0) {
          // pre-scale Q by 0.125 * log2(e): softmax runs in base-2 domain
          qo[(bh * 2048 + t) * 64 + hd] = __float2bfloat16(acc[mf][nf][r] * 0.18033688f);
        } else if (s == 1) {
          ko[(bh * 2048 + t) * 64 + hd] = __float2bfloat16(acc[mf][nf][r]);
        } else {
          vto[(bh * 64 + hd) * 2048 + t] = __float2bfloat16(acc[mf][nf][r]);
        }
      }
}

// ---------------- stage 2: flash attention ----------------
// 512 blocks x 512 threads (8 waves). Q-tile 256 rows (32/wave). KV tile 64.
// bid: bh = bid&63, p = bid>>6 mapped so CU pairs (e,7-e) have equal totals.
// T4 pipeline: 3 LDS KV buffers, loads issued 2 tiles ahead, counted
// s_waitcnt vmcnt(2) + raw s_barrier per tile -- NO vmcnt(0) drain in the
// loop (rounds 4-8 drained the just-issued prefetch every tile via
// __syncthreads, exposing full memory latency per tile).
// Race-freedom: body = [wait][barrier][compute t][issue t+2]; barrier
// bounds wave drift to 1 iter; writer buf (t+2)%3 differs from any buf
// read by a <=1-iter-behind wave. Per-wave vmcnt verifies own loads;
// barrier makes that collective.
// XOR swizzle both-sides (rule 21). Base-2 softmax, T13 defer-rescale,
// deferred l-reduction. P round-trip sliced per mf (16-row slice reused;
// same-wave DS ordering handles the WAR).
__global__ __launch_bounds__(512) void k_attn(
    const __hip_bfloat16* __restrict__ Q, const __hip_bfloat16* __restrict__ K,
    const __hip_bfloat16* __restrict__ VT, __hip_bfloat16* __restrict__ Y) {
  __shared__ __align__(16) __hip_bfloat16 Kl[3][64 * 64];
  __shared__ __align__(16) __hip_bfloat16 Vl[3][64 * 64];   // [d][key]
  __shared__ __align__(16) __hip_bfloat16 Pl[8][16 * 64];
  const int tid = threadIdx.x, lane = tid & 63, wid = tid >> 6;
  const int lr = lane & 15, lk = lane >> 4;

  const int bid = blockIdx.x;
  const int bh = bid & 63;
  const int p = bid >> 6;            // 0..7
  const int e = p & 3;
  const int x = (p < 4) ? p : 7 - e; // CU gets {e, 7-e}: 36 tiles total
  const int q0 = x * 256;
  const int qb = q0 + wid * 32;
  const size_t base = (size_t)bh * 2048 * 64;

  // staging geometry: 512 chunks of 16B per 64x64 tile, 1 per thread
  const int srow = tid >> 3;                       // 0..63
  const int scol = ((tid & 7) ^ (srow & 7)) * 8;   // pre-swizzled source col
  const __hip_bfloat16* kg = K + base + scol;
  const __hip_bfloat16* vg = VT + base + (size_t)srow * 2048 + scol;

  short8 qf[2][2];
#pragma unroll
  for (int mf = 0; mf < 2; mf++)
#pragma unroll
    for (int ks = 0; ks < 2; ks++)
      qf[mf][ks] = *(const short8*)(Q + base + (size_t)(qb + mf * 16 + lr) * 64 + ks * 32 + lk * 8);

  const f32x4 fzero = {0.f, 0.f, 0.f, 0.f};
  f32x4 o[2][4];
  float mrow[2][4], lrow[2][4];
#pragma unroll
  for (int mf = 0; mf < 2; mf++) {
#pragma unroll
    for (int nf = 0; nf < 4; nf++) o[mf][nf] = fzero;
#pragma unroll
    for (int r = 0; r < 4; r++) { mrow[mf][r] = -1e30f; lrow[mf][r] = 0.f; }
  }

  const int nkv = x * 4 + 4;   // >= 4
  // prologue: stage tiles 0,1 into bufs 0,1 (no wait here)
  gload_lds16(kg + (size_t)srow * 64, (void*)(&Kl[0][0] + (tid & ~63) * 8));
  gload_lds16(vg, (void*)(&Vl[0][0] + (tid & ~63) * 8));
  gload_lds16(kg + (size_t)(64 + srow) * 64, (void*)(&Kl[1][0] + (tid & ~63) * 8));
  gload_lds16(vg + 64, (void*)(&Vl[1][0] + (tid & ~63) * 8));

  int cur = 0;
  for (int kt = 0; kt < nkv; ++kt) {
    const int k0 = kt * 64;
    // wait for OWN tile-kt loads (oldest 2 of <=4 outstanding), then join.
    if (kt + 1 < nkv) { asm volatile("s_waitcnt vmcnt(2)" ::: "memory"); }
    else              { asm volatile("s_waitcnt vmcnt(0)" ::: "memory"); }
    __builtin_amdgcn_s_barrier();
    __builtin_amdgcn_sched_barrier(0);

    if (k0 <= qb + 31) {   // wave-uniform: skip fully-masked tiles
      f32x4 s[2][4];
#pragma unroll
      for (int mf = 0; mf < 2; mf++)
#pragma unroll
        for (int nf = 0; nf < 4; nf++) s[mf][nf] = fzero;
      __builtin_amdgcn_s_setprio(1);
#pragma unroll
      for (int ks = 0; ks < 2; ks++) {
        short8 kb[4];
#pragma unroll
        for (int nf = 0; nf < 4; nf++) {
          const int r = nf * 16 + lr;
          kb[nf] = *(const short8*)(&Kl[cur][0] + r * 64 + (((ks * 4 + lk) ^ (r & 7)) * 8));
        }
#pragma unroll
        for (int mf = 0; mf < 2; mf++)
#pragma unroll
          for (int nf = 0; nf < 4; nf++)
            s[mf][nf] = __builtin_amdgcn_mfma_f32_16x16x32_bf16(qf[mf][ks], kb[nf], s[mf][nf], 0, 0, 0);
      }
      __builtin_amdgcn_s_setprio(0);

      const bool needmask = (k0 + 63 > qb);   // wave-uniform: diagonal tile?

      // per-mf: softmax 4 rows -> P slice -> PV  (Pl slice reused across mf)
#pragma unroll
      for (int mf = 0; mf < 2; mf++) {
#pragma unroll
        for (int r = 0; r < 4; r++) {
          const int rowg = qb + mf * 16 + lk * 4 + r;
          const int pr = lk * 4 + r;            // 0..15 within slice
          float mx = -1e30f;
          if (needmask) {
#pragma unroll
            for (int nf = 0; nf < 4; nf++) {
              float sv = s[mf][nf][r];
              if (k0 + nf * 16 + lr > rowg) sv = -1e30f;
              s[mf][nf][r] = sv;
              mx = fmaxf(mx, sv);
            }
          } else {
#pragma unroll
            for (int nf = 0; nf < 4; nf++) mx = fmaxf(mx, s[mf][nf][r]);
          }
#pragma unroll
          for (int d = 1; d < 16; d <<= 1) mx = fmaxf(mx, __shfl_xor(mx, d, 64));
          const float mold = mrow[mf][r];
          float rs = 0.f;
          if (__all(mx - mold <= 8.f)) {
            // T13 defer: keep old max, skip rescale (P bounded by 2^8)
#pragma unroll
            for (int nf = 0; nf < 4; nf++) {
              const float pv = EXP2(s[mf][nf][r] - mold);
              rs += pv;
              const int ce = nf * 16 + lr;
              Pl[wid][pr * 64 + (ce ^ ((pr & 7) << 3))] = __float2bfloat16(pv);
            }
            lrow[mf][r] += rs;
          } else {
            const float mnew = fmaxf(mold, mx);
            const float alpha = EXP2(mold - mnew);
#pragma unroll
            for (int nf = 0; nf < 4; nf++) {
              const float pv = EXP2(s[mf][nf][r] - mnew);
              rs += pv;
              const int ce = nf * 16 + lr;
              Pl[wid][pr * 64 + (ce ^ ((pr & 7) << 3))] = __float2bfloat16(pv);
            }
            lrow[mf][r] = lrow[mf][r] * alpha + rs;
            mrow[mf][r] = mnew;
#pragma unroll
            for (int nf = 0; nf < 4; nf++) o[mf][nf][r] *= alpha;
          }
        }

        asm volatile("s_waitcnt lgkmcnt(0)" ::: "memory");
        __builtin_amdgcn_sched_barrier(0);

        // PV for this mf: A = P slice (row = lr), B = V^T rows d
        __builtin_amdgcn_s_setprio(1);
#pragma unroll
        for (int ks = 0; ks < 2; ks++) {
          short8 pa, vb[4];
          pa = *(const short8*)(&Pl[wid][0] + lr * 64 + (((ks * 4 + lk) ^ (lr & 7)) * 8));
#pragma unroll
          for (int nf = 0; nf < 4; nf++) {
            const int d = nf * 16 + lr;
            vb[nf] = *(const short8*)(&Vl[cur][0] + d * 64 + (((ks * 4 + lk) ^ (d & 7)) * 8));
          }
#pragma unroll
          for (int nf = 0; nf < 4; nf++)
            o[mf][nf] = __builtin_amdgcn_mfma_f32_16x16x32_bf16(pa, vb[nf], o[mf][nf], 0, 0, 0);
        }
        __builtin_amdgcn_s_setprio(0);
      }
    }

    // issue tile kt+2 into buf (cur+2)%3 AFTER compute (3-buf race-freedom)
    if (kt + 2 < nkv) {
      const int kn = (kt + 2) * 64;
      int tb = cur + 2; if (tb >= 3) tb -= 3;
      gload_lds16(kg + (size_t)(kn + srow) * 64, (void*)(&Kl[tb][0] + (tid & ~63) * 8));
      gload_lds16(vg + kn, (void*)(&Vl[tb][0] + (tid & ~63) * 8));
    }
    cur = (cur + 1 == 3) ? 0 : cur + 1;
  }

  const int b = bh >> 4, h = bh & 15;
#pragma unroll
  for (int mf = 0; mf < 2; mf++)
#pragma unroll
    for (int r = 0; r < 4; r++) {
      // deferred l reduction: sum per-lane partials across the 16-lane group
      float ls = lrow[mf][r];
#pragma unroll
      for (int d = 1; d < 16; d <<= 1) ls += __shfl_xor(ls, d, 64);
      const float inv = 1.f / ls;
      const int t = qb + mf * 16 + lk * 4 + r;
#pragma unroll
      for (int nf = 0; nf < 4; nf++)
        Y[((size_t)b * 2048 + t) * 1024 + h * 64 + nf * 16 + lr] =
            __float2bfloat16(o[mf][nf][r] * inv);
    }
}

// ---------------- stage 3: output GEMM ----------------
__global__ __launch_bounds__(256) void k_gemm_out(
    const __hip_bfloat16* __restrict__ X, const __hip_bfloat16* __restrict__ W,
    void* __restrict__ out, const int* __restrict__ flag) {
  __shared__ __align__(16) __hip_bfloat16 As[128 * 32];
  __shared__ __align__(16) __hip_bfloat16 Bs[128 * 32];
  const int tid = threadIdx.x;
  const int lane = tid & 63;
  const int wid = tid >> 6;
  const int wr = wid >> 1, wc = wid & 1;
  const int lr = lane & 15, lk = lane >> 4;
  const int m0 = blockIdx.x * 128;
  const int n0 = blockIdx.y * 128;

  const f32x4 fzero = {0.f, 0.f, 0.f, 0.f};
  f32x4 acc[4][4];
#pragma unroll
  for (int i = 0; i < 4; i++)
#pragma unroll
    for (int j = 0; j < 4; j++) acc[i][j] = fzero;

  for (int kt = 0; kt < 32; ++kt) {
    const int k0 = kt * 32;
    __syncthreads();
#pragma unroll
    for (int j = 0; j < 2; ++j) {
      const int idx = j * 256 + tid;
      const int row = idx >> 2;
      const int ce = (idx & 3) * 8;
      gload_lds16(X + (size_t)(m0 + row) * 1024 + k0 + ce,
                  (void*)(As + (size_t)(j * 256 + (tid & ~63)) * 8));
      gload_lds16(W + (size_t)(n0 + row) * 1024 + k0 + ce,
                  (void*)(Bs + (size_t)(j * 256 + (tid & ~63)) * 8));
    }
    __syncthreads();
    short8 a[4], b[4];
#pragma unroll
    for (int i = 0; i < 4; i++) a[i] = *(const short8*)(As + (wr * 64 + i * 16 + lr) * 32 + lk * 8);
#pragma unroll
    for (int i = 0; i < 4; i++) b[i] = *(const short8*)(Bs + (wc * 64 + i * 16 + lr) * 32 + lk * 8);
#pragma unroll
    for (int mf = 0; mf < 4; mf++)
#pragma unroll
      for (int nf = 0; nf < 4; nf++)
        acc[mf][nf] = __builtin_amdgcn_mfma_f32_16x16x32_bf16(a[mf], b[nf], acc[mf][nf], 0, 0, 0);
  }
  const int f = *flag;
#pragma unroll
  for (int mf = 0; mf < 4; mf++)
#pragma unroll
    for (int nf = 0; nf < 4; nf++)
#pragma unroll
      for (int r = 0; r < 4; r++) {
        const int row = m0 + wr * 64 + mf * 16 + lk * 4 + r;
        const int col = n0 + wc * 64 + nf * 16 + lr;
        const size_t oi = (size_t)row * 1024 + col;
        if (f) ((__hip_bfloat16*)out)[oi] = __float2bfloat16(acc[mf][nf][r]);
        else   ((float*)out)[oi] = acc[mf][nf][r];
      }
}

// ---------------- launch ----------------
extern "C" void kernel_launch(void* const* d_in, const int* in_sizes, int n_in,
                              void* d_out, int out_size, void* d_ws, size_t ws_size,
                              hipStream_t stream) {
  const void* x = d_in[0];     // [4,2048,1024]
  const void* wqkv = d_in[1];  // [3072,1024]
  const void* wo = d_in[2];    // [1024,1024]

  char* ws = (char*)d_ws;
  int* flag = (int*)ws;
  __hip_bfloat16* xb    = (__hip_bfloat16*)(ws + 256);
  __hip_bfloat16* wqkvb = xb + 8388608;
  __hip_bfloat16* wob   = wqkvb + 3145728;
  __hip_bfloat16* qws   = wob + 1048576;
  __hip_bfloat16* kws   = qws + 8388608;   // 64*2048*64
  __hip_bfloat16* vtws  = kws + 8388608;
  __hip_bfloat16* yws   = xb;              // alias: xb dead after QKV GEMM
  // peak ws use: ~72 MB

  k_detect<<<1, 256, 0, stream>>>((const unsigned int*)x, flag);
  k_convert3<<<2048, 256, 0, stream>>>(x, wqkv, wo, (unsigned short*)xb, flag);

  dim3 g1(64, 24);
  k_gemm_qkv<<<g1, 256, 0, stream>>>(xb, wqkvb, qws, kws, vtws);

  k_attn<<<512, 512, 0, stream>>>(qws, kws, vtws, yws);

  dim3 g3(64, 8);
  k_gemm_out<<<g3, 256, 0, stream>>>(yws, wob, d_out, flag);
}

// Round 10
// 188.140 us; speedup vs baseline: 2.3371x; 1.3279x over previous
//
#include <hip/hip_runtime.h>
#include <hip/hip_bf16.h>
#include <stdint.h>

// Fused causal attention block: qkv proj -> flash attention -> out proj.
// B=4 T=2048 C=1024 H=16 HD=64.  All MFMA 16x16x32 bf16, fp32 accum.
// Q pre-scaled by 0.125*log2(e); base-2 softmax via raw v_exp_f32; T13.
// attn: T12 swapped-QK^T fully in-register softmax (no LDS P, no sum
// shuffles) + permuted A-row K reads so PV B-frags are lane-local.

typedef __attribute__((ext_vector_type(8))) short short8;
typedef __attribute__((ext_vector_type(4))) float f32x4;
typedef __attribute__((ext_vector_type(4))) float float4v;
typedef __attribute__((ext_vector_type(4))) unsigned short ushort4v;
typedef __attribute__((ext_vector_type(4))) unsigned int u32x4;

#define AS1 __attribute__((address_space(1)))
#define AS3 __attribute__((address_space(3)))

#if __has_builtin(__builtin_amdgcn_exp2f)
#define EXP2(x) __builtin_amdgcn_exp2f(x)
#else
#define EXP2(x) __expf((x) * 0.69314718f)
#endif

static __device__ __forceinline__ void gload_lds16(const void* g, void* l) {
  __builtin_amdgcn_global_load_lds((const AS1 void*)g, (AS3 void*)l, 16, 0, 0);
}

// ---------------- dtype detect ----------------
__global__ void k_detect(const unsigned int* __restrict__ x, int* __restrict__ flag) {
  __shared__ int sm[256];
  int c = 0;
  for (int i = 0; i < 8; ++i) {
    unsigned int v = x[threadIdx.x * 8 + i];
    unsigned int e = (v >> 7) & 0xffu;
    if (e >= 110u && e <= 140u) c++;
  }
  sm[threadIdx.x] = c;
  __syncthreads();
  if (threadIdx.x == 0) {
    int t = 0;
    for (int i = 0; i < 256; ++i) t += sm[i];
    *flag = (t > 1024) ? 1 : 0;   // 1 = inputs are bf16, 0 = fp32
  }
}

// ---------------- fused convert: x | wqkv | wo -> contiguous bf16 ws ----------------
__global__ void k_convert3(const void* __restrict__ xs, const void* __restrict__ wqs,
                           const void* __restrict__ wos, unsigned short* __restrict__ out,
                           const int* __restrict__ flag) {
  const int f = *flag;
  const int stride = gridDim.x * blockDim.x;
  for (int v = blockIdx.x * blockDim.x + threadIdx.x; v < 3145728; v += stride) {
    const int i = v * 4;
    const void* src; int j;
    if (i < 8388608)        { src = xs;  j = i; }
    else if (i < 11534336)  { src = wqs; j = i - 8388608; }
    else                    { src = wos; j = i - 11534336; }
    ushort4v r;
    if (f) {
      r = *(const ushort4v*)((const unsigned short*)src + j);
    } else {
      float4v fv = *(const float4v*)((const float*)src + j);
#pragma unroll
      for (int e = 0; e < 4; e++) {
        __hip_bfloat16 h = __float2bfloat16(fv[e]);
        r[e] = *(unsigned short*)&h;
      }
    }
    *(ushort4v*)(out + i) = r;
  }
}

// ---------------- stage 1: QKV GEMM ----------------
__global__ __launch_bounds__(256) void k_gemm_qkv(
    const __hip_bfloat16* __restrict__ X, const __hip_bfloat16* __restrict__ W,
    __hip_bfloat16* __restrict__ qo, __hip_bfloat16* __restrict__ ko,
    __hip_bfloat16* __restrict__ vto) {
  __shared__ __align__(16) __hip_bfloat16 As[128 * 32];
  __shared__ __align__(16) __hip_bfloat16 Bs[128 * 32];
  const int tid = threadIdx.x;
  const int lane = tid & 63;
  const int wid = tid >> 6;
  const int wr = wid >> 1, wc = wid & 1;
  const int lr = lane & 15, lk = lane >> 4;
  const int m0 = blockIdx.x * 128;
  const int n0 = blockIdx.y * 128;

  const f32x4 fzero = {0.f, 0.f, 0.f, 0.f};
  f32x4 acc[4][4];
#pragma unroll
  for (int i = 0; i < 4; i++)
#pragma unroll
    for (int j = 0; j < 4; j++) acc[i][j] = fzero;

  for (int kt = 0; kt < 32; ++kt) {
    const int k0 = kt * 32;
    __syncthreads();
#pragma unroll
    for (int j = 0; j < 2; ++j) {
      const int idx = j * 256 + tid;
      const int row = idx >> 2;
      const int ce = (idx & 3) * 8;
      gload_lds16(X + (size_t)(m0 + row) * 1024 + k0 + ce,
                  (void*)(As + (size_t)(j * 256 + (tid & ~63)) * 8));
      gload_lds16(W + (size_t)(n0 + row) * 1024 + k0 + ce,
                  (void*)(Bs + (size_t)(j * 256 + (tid & ~63)) * 8));
    }
    __syncthreads();
    short8 a[4], b[4];
#pragma unroll
    for (int i = 0; i < 4; i++) a[i] = *(const short8*)(As + (wr * 64 + i * 16 + lr) * 32 + lk * 8);
#pragma unroll
    for (int i = 0; i < 4; i++) b[i] = *(const short8*)(Bs + (wc * 64 + i * 16 + lr) * 32 + lk * 8);
#pragma unroll
    for (int mf = 0; mf < 4; mf++)
#pragma unroll
      for (int nf = 0; nf < 4; nf++)
        acc[mf][nf] = __builtin_amdgcn_mfma_f32_16x16x32_bf16(a[mf], b[nf], acc[mf][nf], 0, 0, 0);
  }
#pragma unroll
  for (int mf = 0; mf < 4; mf++)
#pragma unroll
    for (int nf = 0; nf < 4; nf++)
#pragma unroll
      for (int r = 0; r < 4; r++) {
        const int row = m0 + wr * 64 + mf * 16 + lk * 4 + r;  // b*T+t
        const int col = n0 + wc * 64 + nf * 16 + lr;          // [0,3072)
        const int s = col >> 10;
        const int rem = col & 1023;
        const int h = rem >> 6, hd = rem & 63;
        const int bb = row >> 11, t = row & 2047;
        const size_t bh = (size_t)(bb * 16 + h);
        if (s == 0) {
          // pre-scale Q by 0.125 * log2(e): softmax runs in base-2 domain
          qo[(bh * 2048 + t) * 64 + hd] = __float2bfloat16(acc[mf][nf][r] * 0.18033688f);
        } else if (s == 1) {
          ko[(bh * 2048 + t) * 64 + hd] = __float2bfloat16(acc[mf][nf][r]);
        } else {
          vto[(bh * 64 + hd) * 2048 + t] = __float2bfloat16(acc[mf][nf][r]);
        }
      }
}

// ---------------- stage 2: flash attention (T12 swapped QK^T) ----------------
// 512 blocks x 512 threads (8 waves). Q-tile 256 rows (32/wave). KV tile 64.
// bh = bid&63, p = bid>>6 mapped so CU pairs (e,7-e) have equal totals.
// R9 pipeline kept: 3 LDS KV buffers, issue 2 ahead, counted vmcnt(2).
// Swapped QK^T: C = mfma(A=K, B=Q) -> lane owns one q (col=lr), 16 k's.
// A-row permutation f(a,i) = (i>>2)*8 + (a&1)*4 + (i&3) + (a>>1)*32 makes
// lane lk's C regs = exactly k = {lk*8..+7} (+32) -> PV B-frag is built
// IN-LANE (no LDS P, no cross-lane moves). Softmax: 2 shfl per q-group
// (max only); l-sum deferred per-lane to epilogue. O comes out transposed
// -> LDS transpose epilogue (bank-XOR'd) -> coalesced 16B Y stores.
// LDS swizzle F(r) = (r&7) ^ (2*(r>>3) & 7) keeps kb/vb reads uniform.
__global__ __launch_bounds__(512) void k_attn(
    const __hip_bfloat16* __restrict__ Q, const __hip_bfloat16* __restrict__ K,
    const __hip_bfloat16* __restrict__ VT, __hip_bfloat16* __restrict__ Y) {
  __shared__ __align__(16) char smem[49152];   // K bufs 0..2 | V bufs 0..2
  char* smc = smem;
  const int tid = threadIdx.x, lane = tid & 63, wid = tid >> 6;
  const int lr = lane & 15, lk = lane >> 4;

  const int bid = blockIdx.x;
  const int bh = bid & 63;
  const int p = bid >> 6;            // 0..7
  const int e = p & 3;
  const int x = (p < 4) ? p : 7 - e; // CU gets {e, 7-e}: 36 tiles total
  const int q0 = x * 256;
  const int qb = q0 + wid * 32;
  const size_t base = (size_t)bh * 2048 * 64;

  // staging: 512 chunks of 16B per 64x64 tile, source pre-swizzled by F
  const int srow = tid >> 3;                        // 0..63
  const int fs = (srow & 7) ^ ((2 * (srow >> 3)) & 7);
  const int scol = ((tid & 7) ^ fs) * 8;
  const __hip_bfloat16* kg = K + base + scol;
  const __hip_bfloat16* vg = VT + base + (size_t)srow * 2048 + scol;
  const int ldst = (tid & ~63) * 16;                // wave-uniform LDS dest

  // per-lane read offsets (bytes within an 8KB buffer)
  int koff[4][2], voff[4][2], kla[4];
#pragma unroll
  for (int a = 0; a < 4; a++) {
    const int ra = (lr >> 2) * 8 + (a & 1) * 4 + (lr & 3) + (a >> 1) * 32;
    const int fr = (ra & 7) ^ ((2 * (ra >> 3)) & 7);
    kla[a] = lk * 8 + (a & 1) * 4 + (a >> 1) * 32;
#pragma unroll
    for (int ks = 0; ks < 2; ks++)
      koff[a][ks] = ra * 128 + (((ks * 4 + lk) ^ fr) * 16);
  }
#pragma unroll
  for (int df = 0; df < 4; df++) {
    const int rv = df * 16 + lr;
    const int fv = (rv & 7) ^ ((2 * (rv >> 3)) & 7);
#pragma unroll
    for (int ks = 0; ks < 2; ks++)
      voff[df][ks] = rv * 128 + (((ks * 4 + lk) ^ fv) * 16);
  }

  short8 qf[2][2];
#pragma unroll
  for (int qg = 0; qg < 2; qg++)
#pragma unroll
    for (int ks = 0; ks < 2; ks++)
      qf[qg][ks] = *(const short8*)(Q + base + (size_t)(qb + qg * 16 + lr) * 64 + ks * 32 + lk * 8);

  const f32x4 fzero = {0.f, 0.f, 0.f, 0.f};
  f32x4 ot[2][4];                     // O^T accum: row d, col q
  float mrow[2] = {-1e30f, -1e30f}, lrow[2] = {0.f, 0.f};
#pragma unroll
  for (int qg = 0; qg < 2; qg++)
#pragma unroll
    for (int df = 0; df < 4; df++) ot[qg][df] = fzero;

  const int nkv = x * 4 + 4;
  // prologue: stage tiles 0,1 into bufs 0,1
  gload_lds16(kg + (size_t)srow * 64, (void*)(smc + ldst));
  gload_lds16(vg, (void*)(smc + 24576 + ldst));
  gload_lds16(kg + (size_t)(64 + srow) * 64, (void*)(smc + 8192 + ldst));
  gload_lds16(vg + 64, (void*)(smc + 24576 + 8192 + ldst));

  int cur = 0;
  for (int kt = 0; kt < nkv; ++kt) {
    const int k0 = kt * 64;
    if (kt + 1 < nkv) { asm volatile("s_waitcnt vmcnt(2)" ::: "memory"); }
    else              { asm volatile("s_waitcnt vmcnt(0)" ::: "memory"); }
    __builtin_amdgcn_s_barrier();
    __builtin_amdgcn_sched_barrier(0);

    if (k0 <= qb + 31) {   // wave-uniform: skip fully-masked tiles
      const char* kbuf = smc + cur * 8192;
      const char* vbuf = smc + 24576 + cur * 8192;

      f32x4 s[2][4];
#pragma unroll
      for (int qg = 0; qg < 2; qg++)
#pragma unroll
        for (int a = 0; a < 4; a++) s[qg][a] = fzero;

      __builtin_amdgcn_s_setprio(1);
#pragma unroll
      for (int ks = 0; ks < 2; ks++)
#pragma unroll
        for (int a = 0; a < 4; a++) {
          const short8 kb = *(const short8*)(kbuf + koff[a][ks]);
          s[0][a] = __builtin_amdgcn_mfma_f32_16x16x32_bf16(kb, qf[0][ks], s[0][a], 0, 0, 0);
          s[1][a] = __builtin_amdgcn_mfma_f32_16x16x32_bf16(kb, qf[1][ks], s[1][a], 0, 0, 0);
        }
      __builtin_amdgcn_s_setprio(0);

      const bool needmask = (k0 + 63 > qb);
      short8 pb[2][2];

#pragma unroll
      for (int qg = 0; qg < 2; qg++) {
        const int qq = qb + qg * 16 + lr;
        if (needmask) {
#pragma unroll
          for (int a = 0; a < 4; a++)
#pragma unroll
            for (int r = 0; r < 4; r++)
              if (k0 + kla[a] + r > qq) s[qg][a][r] = -1e30f;
        }
        // in-lane max over 16, then 2 shfl across lk groups
        f32x4 m4;
#pragma unroll
        for (int r = 0; r < 4; r++)
          m4[r] = fmaxf(fmaxf(s[qg][0][r], s[qg][1][r]), fmaxf(s[qg][2][r], s[qg][3][r]));
        float mx = fmaxf(fmaxf(m4[0], m4[1]), fmaxf(m4[2], m4[3]));
        mx = fmaxf(mx, __shfl_xor(mx, 16, 64));
        mx = fmaxf(mx, __shfl_xor(mx, 32, 64));
        const float mold = mrow[qg];
        float m;
        if (__all(mx - mold <= 8.f)) {
          m = mold;            // T13 defer: P bounded by 2^8
        } else {
          m = fmaxf(mold, mx);
          const float alpha = EXP2(mold - m);
          lrow[qg] *= alpha;
          mrow[qg] = m;
#pragma unroll
          for (int df = 0; df < 4; df++) ot[qg][df] *= alpha;
        }
        float rs = 0.f;
#pragma unroll
        for (int a = 0; a < 4; a++)
#pragma unroll
          for (int r = 0; r < 4; r++) {
            const float pv = EXP2(s[qg][a][r] - m);
            s[qg][a][r] = pv;
            rs += pv;
          }
        lrow[qg] += rs;        // per-lane partial; cross-lane at epilogue
        // pack PV B-frags: e<4 from block 2ksP, e>=4 from 2ksP+1 (in-lane!)
#pragma unroll
        for (int ksP = 0; ksP < 2; ksP++) {
          short8 w;
#pragma unroll
          for (int ee = 0; ee < 4; ee++) {
            __hip_bfloat16 h0 = __float2bfloat16(s[qg][2 * ksP][ee]);
            __hip_bfloat16 h1 = __float2bfloat16(s[qg][2 * ksP + 1][ee]);
            w[ee] = *(short*)&h0;
            w[4 + ee] = *(short*)&h1;
          }
          pb[qg][ksP] = w;
        }
      }

      // PV: o^T[d][q] += V^T[d][k] * P[k][q]
      __builtin_amdgcn_s_setprio(1);
#pragma unroll
      for (int ks = 0; ks < 2; ks++)
#pragma unroll
        for (int df = 0; df < 4; df++) {
          const short8 vb = *(const short8*)(vbuf + voff[df][ks]);
          ot[0][df] = __builtin_amdgcn_mfma_f32_16x16x32_bf16(vb, pb[0][ks], ot[0][df], 0, 0, 0);
          ot[1][df] = __builtin_amdgcn_mfma_f32_16x16x32_bf16(vb, pb[1][ks], ot[1][df], 0, 0, 0);
        }
      __builtin_amdgcn_s_setprio(0);
    }

    // issue tile kt+2 into buf (cur+2)%3 AFTER compute (3-buf race-freedom)
    if (kt + 2 < nkv) {
      const int kn = (kt + 2) * 64;
      int tb = cur + 2; if (tb >= 3) tb -= 3;
      gload_lds16(kg + (size_t)(kn + srow) * 64, (void*)(smc + tb * 8192 + ldst));
      gload_lds16(vg + kn, (void*)(smc + 24576 + tb * 8192 + ldst));
    }
    cur = (cur + 1 == 3) ? 0 : cur + 1;
  }

  // ---- epilogue: normalize, transpose through LDS, coalesced store ----
  __syncthreads();                      // all waves done with K/V buffers
  unsigned int* Os = (unsigned int*)smc; // 256 rows x 32 u32 = 32 KB
#pragma unroll
  for (int qg = 0; qg < 2; qg++) {
    float ls = lrow[qg];
    ls += __shfl_xor(ls, 16, 64);
    ls += __shfl_xor(ls, 32, 64);
    const float inv = 1.f / ls;
    const int qlocal = wid * 32 + qg * 16 + lr;
    const int sw = (lr & 7) << 2;
#pragma unroll
    for (int df = 0; df < 4; df++)
#pragma unroll
      for (int e2 = 0; e2 < 2; e2++) {
        __hip_bfloat16 h0 = __float2bfloat16(ot[qg][df][2 * e2] * inv);
        __hip_bfloat16 h1 = __float2bfloat16(ot[qg][df][2 * e2 + 1] * inv);
        const unsigned int w = (unsigned int)*(unsigned short*)&h0 |
                               ((unsigned int)*(unsigned short*)&h1 << 16);
        Os[qlocal * 32 + ((df * 8 + lk * 2 + e2) ^ sw)] = w;
      }
  }
  __syncthreads();
  {
    const int qrow = tid >> 1, half = tid & 1, q7 = qrow & 7;
    const int b = bh >> 4, h = bh & 15;
    unsigned int* Yu = (unsigned int*)Y;
    const size_t rowbase = ((size_t)b * 2048 + q0 + qrow) * 512 + h * 32;
#pragma unroll
    for (int g = 0; g < 4; g++) {
      const int cg = half * 4 + g;
      const u32x4 v = *(const u32x4*)(smc + qrow * 128 + ((cg ^ q7) * 16));
      *(u32x4*)(Yu + rowbase + cg * 4) = v;
    }
  }
}

// ---------------- stage 3: output GEMM ----------------
__global__ __launch_bounds__(256) void k_gemm_out(
    const __hip_bfloat16* __restrict__ X, const __hip_bfloat16* __restrict__ W,
    void* __restrict__ out, const int* __restrict__ flag) {
  __shared__ __align__(16) __hip_bfloat16 As[128 * 32];
  __shared__ __align__(16) __hip_bfloat16 Bs[128 * 32];
  const int tid = threadIdx.x;
  const int lane = tid & 63;
  const int wid = tid >> 6;
  const int wr = wid >> 1, wc = wid & 1;
  const int lr = lane & 15, lk = lane >> 4;
  const int m0 = blockIdx.x * 128;
  const int n0 = blockIdx.y * 128;

  const f32x4 fzero = {0.f, 0.f, 0.f, 0.f};
  f32x4 acc[4][4];
#pragma unroll
  for (int i = 0; i < 4; i++)
#pragma unroll
    for (int j = 0; j < 4; j++) acc[i][j] = fzero;

  for (int kt = 0; kt < 32; ++kt) {
    const int k0 = kt * 32;
    __syncthreads();
#pragma unroll
    for (int j = 0; j < 2; ++j) {
      const int idx = j * 256 + tid;
      const int row = idx >> 2;
      const int ce = (idx & 3) * 8;
      gload_lds16(X + (size_t)(m0 + row) * 1024 + k0 + ce,
                  (void*)(As + (size_t)(j * 256 + (tid & ~63)) * 8));
      gload_lds16(W + (size_t)(n0 + row) * 1024 + k0 + ce,
                  (void*)(Bs + (size_t)(j * 256 + (tid & ~63)) * 8));
    }
    __syncthreads();
    short8 a[4], b[4];
#pragma unroll
    for (int i = 0; i < 4; i++) a[i] = *(const short8*)(As + (wr * 64 + i * 16 + lr) * 32 + lk * 8);
#pragma unroll
    for (int i = 0; i < 4; i++) b[i] = *(const short8*)(Bs + (wc * 64 + i * 16 + lr) * 32 + lk * 8);
#pragma unroll
    for (int mf = 0; mf < 4; mf++)
#pragma unroll
      for (int nf = 0; nf < 4; nf++)
        acc[mf][nf] = __builtin_amdgcn_mfma_f32_16x16x32_bf16(a[mf], b[nf], acc[mf][nf], 0, 0, 0);
  }
  const int f = *flag;
#pragma unroll
  for (int mf = 0; mf < 4; mf++)
#pragma unroll
    for (int nf = 0; nf < 4; nf++)
#pragma unroll
      for (int r = 0; r < 4; r++) {
        const int row = m0 + wr * 64 + mf * 16 + lk * 4 + r;
        const int col = n0 + wc * 64 + nf * 16 + lr;
        const size_t oi = (size_t)row * 1024 + col;
        if (f) ((__hip_bfloat16*)out)[oi] = __float2bfloat16(acc[mf][nf][r]);
        else   ((float*)out)[oi] = acc[mf][nf][r];
      }
}

// ---------------- launch ----------------
extern "C" void kernel_launch(void* const* d_in, const int* in_sizes, int n_in,
                              void* d_out, int out_size, void* d_ws, size_t ws_size,
                              hipStream_t stream) {
  const void* x = d_in[0];     // [4,2048,1024]
  const void* wqkv = d_in[1];  // [3072,1024]
  const void* wo = d_in[2];    // [1024,1024]

  char* ws = (char*)d_ws;
  int* flag = (int*)ws;
  __hip_bfloat16* xb    = (__hip_bfloat16*)(ws + 256);
  __hip_bfloat16* wqkvb = xb + 8388608;
  __hip_bfloat16* wob   = wqkvb + 3145728;
  __hip_bfloat16* qws   = wob + 1048576;
  __hip_bfloat16* kws   = qws + 8388608;   // 64*2048*64
  __hip_bfloat16* vtws  = kws + 8388608;
  __hip_bfloat16* yws   = xb;              // alias: xb dead after QKV GEMM
  // peak ws use: ~72 MB

  k_detect<<<1, 256, 0, stream>>>((const unsigned int*)x, flag);
  k_convert3<<<2048, 256, 0, stream>>>(x, wqkv, wo, (unsigned short*)xb, flag);

  dim3 g1(64, 24);
  k_gemm_qkv<<<g1, 256, 0, stream>>>(xb, wqkvb, qws, kws, vtws);

  k_attn<<<512, 512, 0, stream>>>(qws, kws, vtws, yws);

  dim3 g3(64, 8);
  k_gemm_out<<<g3, 256, 0, stream>>>(yws, wob, d_out, flag);
}

// Round 11
// 187.397 us; speedup vs baseline: 2.3464x; 1.0040x over previous
//
#include <hip/hip_runtime.h>
#include <hip/hip_bf16.h>
#include <stdint.h>

// Fused causal attention block: qkv proj -> flash attention -> out proj.
// B=4 T=2048 C=1024 H=16 HD=64.  All MFMA 16x16x32 bf16, fp32 accum.
// Q pre-scaled by 0.125*log2(e); base-2 softmax via raw v_exp_f32; T13.
// attn: T12 swapped-QK^T in-register softmax. GEMMs: chunk XOR-swizzle
// (both-sides, s(r)=(r>>1)&3) kills the 8-way LDS bank conflict.

typedef __attribute__((ext_vector_type(8))) short short8;
typedef __attribute__((ext_vector_type(4))) float f32x4;
typedef __attribute__((ext_vector_type(4))) float float4v;
typedef __attribute__((ext_vector_type(4))) unsigned short ushort4v;
typedef __attribute__((ext_vector_type(4))) unsigned int u32x4;

#define AS1 __attribute__((address_space(1)))
#define AS3 __attribute__((address_space(3)))

#if __has_builtin(__builtin_amdgcn_exp2f)
#define EXP2(x) __builtin_amdgcn_exp2f(x)
#else
#define EXP2(x) __expf((x) * 0.69314718f)
#endif

static __device__ __forceinline__ void gload_lds16(const void* g, void* l) {
  __builtin_amdgcn_global_load_lds((const AS1 void*)g, (AS3 void*)l, 16, 0, 0);
}

// ---------------- dtype detect ----------------
__global__ void k_detect(const unsigned int* __restrict__ x, int* __restrict__ flag) {
  __shared__ int sm[256];
  int c = 0;
  for (int i = 0; i < 8; ++i) {
    unsigned int v = x[threadIdx.x * 8 + i];
    unsigned int e = (v >> 7) & 0xffu;
    if (e >= 110u && e <= 140u) c++;
  }
  sm[threadIdx.x] = c;
  __syncthreads();
  if (threadIdx.x == 0) {
    int t = 0;
    for (int i = 0; i < 256; ++i) t += sm[i];
    *flag = (t > 1024) ? 1 : 0;   // 1 = inputs are bf16, 0 = fp32
  }
}

// ---------------- fused convert: x | wqkv | wo -> contiguous bf16 ws ----------------
__global__ void k_convert3(const void* __restrict__ xs, const void* __restrict__ wqs,
                           const void* __restrict__ wos, unsigned short* __restrict__ out,
                           const int* __restrict__ flag) {
  const int f = *flag;
  const int stride = gridDim.x * blockDim.x;
  for (int v = blockIdx.x * blockDim.x + threadIdx.x; v < 3145728; v += stride) {
    const int i = v * 4;
    const void* src; int j;
    if (i < 8388608)        { src = xs;  j = i; }
    else if (i < 11534336)  { src = wqs; j = i - 8388608; }
    else                    { src = wos; j = i - 11534336; }
    ushort4v r;
    if (f) {
      r = *(const ushort4v*)((const unsigned short*)src + j);
    } else {
      float4v fv = *(const float4v*)((const float*)src + j);
#pragma unroll
      for (int e = 0; e < 4; e++) {
        __hip_bfloat16 h = __float2bfloat16(fv[e]);
        r[e] = *(unsigned short*)&h;
      }
    }
    *(ushort4v*)(out + i) = r;
  }
}

// ---------------- stage 1: QKV GEMM ----------------
// LDS chunk swizzle: position p of row r holds global chunk p ^ s(r),
// s(r) = (r>>1)&3. Staged via pre-swizzled SOURCE col (dest linear,
// rule 21); reads use chunk lk ^ s(r). 2 lanes/bank-window = free.
__global__ __launch_bounds__(256) void k_gemm_qkv(
    const __hip_bfloat16* __restrict__ X, const __hip_bfloat16* __restrict__ W,
    __hip_bfloat16* __restrict__ qo, __hip_bfloat16* __restrict__ ko,
    __hip_bfloat16* __restrict__ vto) {
  __shared__ __align__(16) __hip_bfloat16 As[128 * 32];
  __shared__ __align__(16) __hip_bfloat16 Bs[128 * 32];
  const int tid = threadIdx.x;
  const int lane = tid & 63;
  const int wid = tid >> 6;
  const int wr = wid >> 1, wc = wid & 1;
  const int lr = lane & 15, lk = lane >> 4;
  const int m0 = blockIdx.x * 128;
  const int n0 = blockIdx.y * 128;
  const int sw = (lr >> 1) & 3;              // lane-uniform s(r) for reads

  const f32x4 fzero = {0.f, 0.f, 0.f, 0.f};
  f32x4 acc[4][4];
#pragma unroll
  for (int i = 0; i < 4; i++)
#pragma unroll
    for (int j = 0; j < 4; j++) acc[i][j] = fzero;

  for (int kt = 0; kt < 32; ++kt) {
    const int k0 = kt * 32;
    __syncthreads();
#pragma unroll
    for (int j = 0; j < 2; ++j) {
      const int idx = j * 256 + tid;
      const int row = idx >> 2;
      const int ce = ((idx & 3) ^ ((row >> 1) & 3)) * 8;   // pre-swizzled src
      gload_lds16(X + (size_t)(m0 + row) * 1024 + k0 + ce,
                  (void*)(As + (size_t)(j * 256 + (tid & ~63)) * 8));
      gload_lds16(W + (size_t)(n0 + row) * 1024 + k0 + ce,
                  (void*)(Bs + (size_t)(j * 256 + (tid & ~63)) * 8));
    }
    __syncthreads();
    short8 a[4], b[4];
#pragma unroll
    for (int i = 0; i < 4; i++) a[i] = *(const short8*)(As + (wr * 64 + i * 16 + lr) * 32 + ((lk ^ sw) * 8));
#pragma unroll
    for (int i = 0; i < 4; i++) b[i] = *(const short8*)(Bs + (wc * 64 + i * 16 + lr) * 32 + ((lk ^ sw) * 8));
#pragma unroll
    for (int mf = 0; mf < 4; mf++)
#pragma unroll
      for (int nf = 0; nf < 4; nf++)
        acc[mf][nf] = __builtin_amdgcn_mfma_f32_16x16x32_bf16(a[mf], b[nf], acc[mf][nf], 0, 0, 0);
  }
#pragma unroll
  for (int mf = 0; mf < 4; mf++)
#pragma unroll
    for (int nf = 0; nf < 4; nf++)
#pragma unroll
      for (int r = 0; r < 4; r++) {
        const int row = m0 + wr * 64 + mf * 16 + lk * 4 + r;  // b*T+t
        const int col = n0 + wc * 64 + nf * 16 + lr;          // [0,3072)
        const int s = col >> 10;
        const int rem = col & 1023;
        const int h = rem >> 6, hd = rem & 63;
        const int bb = row >> 11, t = row & 2047;
        const size_t bh = (size_t)(bb * 16 + h);
        if (s == 0) {
          // pre-scale Q by 0.125 * log2(e): softmax runs in base-2 domain
          qo[(bh * 2048 + t) * 64 + hd] = __float2bfloat16(acc[mf][nf][r] * 0.18033688f);
        } else if (s == 1) {
          ko[(bh * 2048 + t) * 64 + hd] = __float2bfloat16(acc[mf][nf][r]);
        } else {
          vto[(bh * 64 + hd) * 2048 + t] = __float2bfloat16(acc[mf][nf][r]);
        }
      }
}

// ---------------- stage 2: flash attention (T12 swapped QK^T) ----------------
// 512 blocks x 512 threads (8 waves). Q-tile 256 rows (32/wave). KV tile 64.
// bh = bid&63, p = bid>>6 mapped so CU pairs (e,7-e) have equal totals.
// 3 LDS KV buffers, issue 2 ahead, counted vmcnt(2).
// Swapped QK^T: C = mfma(A=K, B=Q) -> lane owns one q (col=lr), 16 k's.
// A-row permutation f(a,i) = (i>>2)*8 + (a&1)*4 + (i&3) + (a>>1)*32 makes
// lane lk's C regs = exactly k = {lk*8..+7} (+32) -> PV B-frag is built
// IN-LANE (no LDS P, no cross-lane moves). Softmax: 2 shfl per q-group
// (max only); l-sum deferred per-lane to epilogue. O comes out transposed
// -> LDS transpose epilogue (bank-XOR'd) -> coalesced 16B Y stores.
// LDS swizzle F(r) = (r&7) ^ (2*(r>>3) & 7) keeps kb/vb reads uniform.
__global__ __launch_bounds__(512) void k_attn(
    const __hip_bfloat16* __restrict__ Q, const __hip_bfloat16* __restrict__ K,
    const __hip_bfloat16* __restrict__ VT, __hip_bfloat16* __restrict__ Y) {
  __shared__ __align__(16) char smem[49152];   // K bufs 0..2 | V bufs 0..2
  char* smc = smem;
  const int tid = threadIdx.x, lane = tid & 63, wid = tid >> 6;
  const int lr = lane & 15, lk = lane >> 4;

  const int bid = blockIdx.x;
  const int bh = bid & 63;
  const int p = bid >> 6;            // 0..7
  const int e = p & 3;
  const int x = (p < 4) ? p : 7 - e; // CU gets {e, 7-e}: 36 tiles total
  const int q0 = x * 256;
  const int qb = q0 + wid * 32;
  const size_t base = (size_t)bh * 2048 * 64;

  // staging: 512 chunks of 16B per 64x64 tile, source pre-swizzled by F
  const int srow = tid >> 3;                        // 0..63
  const int fs = (srow & 7) ^ ((2 * (srow >> 3)) & 7);
  const int scol = ((tid & 7) ^ fs) * 8;
  const __hip_bfloat16* kg = K + base + scol;
  const __hip_bfloat16* vg = VT + base + (size_t)srow * 2048 + scol;
  const int ldst = (tid & ~63) * 16;                // wave-uniform LDS dest

  // per-lane read offsets (bytes within an 8KB buffer)
  int koff[4][2], voff[4][2], kla[4];
#pragma unroll
  for (int a = 0; a < 4; a++) {
    const int ra = (lr >> 2) * 8 + (a & 1) * 4 + (lr & 3) + (a >> 1) * 32;
    const int fr = (ra & 7) ^ ((2 * (ra >> 3)) & 7);
    kla[a] = lk * 8 + (a & 1) * 4 + (a >> 1) * 32;
#pragma unroll
    for (int ks = 0; ks < 2; ks++)
      koff[a][ks] = ra * 128 + (((ks * 4 + lk) ^ fr) * 16);
  }
#pragma unroll
  for (int df = 0; df < 4; df++) {
    const int rv = df * 16 + lr;
    const int fv = (rv & 7) ^ ((2 * (rv >> 3)) & 7);
#pragma unroll
    for (int ks = 0; ks < 2; ks++)
      voff[df][ks] = rv * 128 + (((ks * 4 + lk) ^ fv) * 16);
  }

  short8 qf[2][2];
#pragma unroll
  for (int qg = 0; qg < 2; qg++)
#pragma unroll
    for (int ks = 0; ks < 2; ks++)
      qf[qg][ks] = *(const short8*)(Q + base + (size_t)(qb + qg * 16 + lr) * 64 + ks * 32 + lk * 8);

  const f32x4 fzero = {0.f, 0.f, 0.f, 0.f};
  f32x4 ot[2][4];                     // O^T accum: row d, col q
  float mrow[2] = {-1e30f, -1e30f}, lrow[2] = {0.f, 0.f};
#pragma unroll
  for (int qg = 0; qg < 2; qg++)
#pragma unroll
    for (int df = 0; df < 4; df++) ot[qg][df] = fzero;

  const int nkv = x * 4 + 4;
  // prologue: stage tiles 0,1 into bufs 0,1
  gload_lds16(kg + (size_t)srow * 64, (void*)(smc + ldst));
  gload_lds16(vg, (void*)(smc + 24576 + ldst));
  gload_lds16(kg + (size_t)(64 + srow) * 64, (void*)(smc + 8192 + ldst));
  gload_lds16(vg + 64, (void*)(smc + 24576 + 8192 + ldst));

  int cur = 0;
  for (int kt = 0; kt < nkv; ++kt) {
    const int k0 = kt * 64;
    if (kt + 1 < nkv) { asm volatile("s_waitcnt vmcnt(2)" ::: "memory"); }
    else              { asm volatile("s_waitcnt vmcnt(0)" ::: "memory"); }
    __builtin_amdgcn_s_barrier();
    __builtin_amdgcn_sched_barrier(0);

    if (k0 <= qb + 31) {   // wave-uniform: skip fully-masked tiles
      const char* kbuf = smc + cur * 8192;
      const char* vbuf = smc + 24576 + cur * 8192;

      f32x4 s[2][4];
#pragma unroll
      for (int qg = 0; qg < 2; qg++)
#pragma unroll
        for (int a = 0; a < 4; a++) s[qg][a] = fzero;

      __builtin_amdgcn_s_setprio(1);
#pragma unroll
      for (int ks = 0; ks < 2; ks++)
#pragma unroll
        for (int a = 0; a < 4; a++) {
          const short8 kb = *(const short8*)(kbuf + koff[a][ks]);
          s[0][a] = __builtin_amdgcn_mfma_f32_16x16x32_bf16(kb, qf[0][ks], s[0][a], 0, 0, 0);
          s[1][a] = __builtin_amdgcn_mfma_f32_16x16x32_bf16(kb, qf[1][ks], s[1][a], 0, 0, 0);
        }
      __builtin_amdgcn_s_setprio(0);

      const bool needmask = (k0 + 63 > qb);
      short8 pb[2][2];

#pragma unroll
      for (int qg = 0; qg < 2; qg++) {
        const int qq = qb + qg * 16 + lr;
        if (needmask) {
#pragma unroll
          for (int a = 0; a < 4; a++)
#pragma unroll
            for (int r = 0; r < 4; r++)
              if (k0 + kla[a] + r > qq) s[qg][a][r] = -1e30f;
        }
        // in-lane max over 16, then 2 shfl across lk groups
        f32x4 m4;
#pragma unroll
        for (int r = 0; r < 4; r++)
          m4[r] = fmaxf(fmaxf(s[qg][0][r], s[qg][1][r]), fmaxf(s[qg][2][r], s[qg][3][r]));
        float mx = fmaxf(fmaxf(m4[0], m4[1]), fmaxf(m4[2], m4[3]));
        mx = fmaxf(mx, __shfl_xor(mx, 16, 64));
        mx = fmaxf(mx, __shfl_xor(mx, 32, 64));
        const float mold = mrow[qg];
        float m;
        if (__all(mx - mold <= 8.f)) {
          m = mold;            // T13 defer: P bounded by 2^8
        } else {
          m = fmaxf(mold, mx);
          const float alpha = EXP2(mold - m);
          lrow[qg] *= alpha;
          mrow[qg] = m;
#pragma unroll
          for (int df = 0; df < 4; df++) ot[qg][df] *= alpha;
        }
        float rs = 0.f;
#pragma unroll
        for (int a = 0; a < 4; a++)
#pragma unroll
          for (int r = 0; r < 4; r++) {
            const float pv = EXP2(s[qg][a][r] - m);
            s[qg][a][r] = pv;
            rs += pv;
          }
        lrow[qg] += rs;        // per-lane partial; cross-lane at epilogue
        // pack PV B-frags: e<4 from block 2ksP, e>=4 from 2ksP+1 (in-lane!)
#pragma unroll
        for (int ksP = 0; ksP < 2; ksP++) {
          short8 w;
#pragma unroll
          for (int ee = 0; ee < 4; ee++) {
            __hip_bfloat16 h0 = __float2bfloat16(s[qg][2 * ksP][ee]);
            __hip_bfloat16 h1 = __float2bfloat16(s[qg][2 * ksP + 1][ee]);
            w[ee] = *(short*)&h0;
            w[4 + ee] = *(short*)&h1;
          }
          pb[qg][ksP] = w;
        }
      }

      // PV: o^T[d][q] += V^T[d][k] * P[k][q]
      __builtin_amdgcn_s_setprio(1);
#pragma unroll
      for (int ks = 0; ks < 2; ks++)
#pragma unroll
        for (int df = 0; df < 4; df++) {
          const short8 vb = *(const short8*)(vbuf + voff[df][ks]);
          ot[0][df] = __builtin_amdgcn_mfma_f32_16x16x32_bf16(vb, pb[0][ks], ot[0][df], 0, 0, 0);
          ot[1][df] = __builtin_amdgcn_mfma_f32_16x16x32_bf16(vb, pb[1][ks], ot[1][df], 0, 0, 0);
        }
      __builtin_amdgcn_s_setprio(0);
    }

    // issue tile kt+2 into buf (cur+2)%3 AFTER compute (3-buf race-freedom)
    if (kt + 2 < nkv) {
      const int kn = (kt + 2) * 64;
      int tb = cur + 2; if (tb >= 3) tb -= 3;
      gload_lds16(kg + (size_t)(kn + srow) * 64, (void*)(smc + tb * 8192 + ldst));
      gload_lds16(vg + kn, (void*)(smc + 24576 + tb * 8192 + ldst));
    }
    cur = (cur + 1 == 3) ? 0 : cur + 1;
  }

  // ---- epilogue: normalize, transpose through LDS, coalesced store ----
  __syncthreads();                      // all waves done with K/V buffers
  unsigned int* Os = (unsigned int*)smc; // 256 rows x 32 u32 = 32 KB
#pragma unroll
  for (int qg = 0; qg < 2; qg++) {
    float ls = lrow[qg];
    ls += __shfl_xor(ls, 16, 64);
    ls += __shfl_xor(ls, 32, 64);
    const float inv = 1.f / ls;
    const int qlocal = wid * 32 + qg * 16 + lr;
    const int sw = (lr & 7) << 2;
#pragma unroll
    for (int df = 0; df < 4; df++)
#pragma unroll
      for (int e2 = 0; e2 < 2; e2++) {
        __hip_bfloat16 h0 = __float2bfloat16(ot[qg][df][2 * e2] * inv);
        __hip_bfloat16 h1 = __float2bfloat16(ot[qg][df][2 * e2 + 1] * inv);
        const unsigned int w = (unsigned int)*(unsigned short*)&h0 |
                               ((unsigned int)*(unsigned short*)&h1 << 16);
        Os[qlocal * 32 + ((df * 8 + lk * 2 + e2) ^ sw)] = w;
      }
  }
  __syncthreads();
  {
    const int qrow = tid >> 1, half = tid & 1, q7 = qrow & 7;
    const int b = bh >> 4, h = bh & 15;
    unsigned int* Yu = (unsigned int*)Y;
    const size_t rowbase = ((size_t)b * 2048 + q0 + qrow) * 512 + h * 32;
#pragma unroll
    for (int g = 0; g < 4; g++) {
      const int cg = half * 4 + g;
      const u32x4 v = *(const u32x4*)(smc + qrow * 128 + ((cg ^ q7) * 16));
      *(u32x4*)(Yu + rowbase + cg * 4) = v;
    }
  }
}

// ---------------- stage 3: output GEMM ----------------
__global__ __launch_bounds__(256) void k_gemm_out(
    const __hip_bfloat16* __restrict__ X, const __hip_bfloat16* __restrict__ W,
    void* __restrict__ out, const int* __restrict__ flag) {
  __shared__ __align__(16) __hip_bfloat16 As[128 * 32];
  __shared__ __align__(16) __hip_bfloat16 Bs[128 * 32];
  const int tid = threadIdx.x;
  const int lane = tid & 63;
  const int wid = tid >> 6;
  const int wr = wid >> 1, wc = wid & 1;
  const int lr = lane & 15, lk = lane >> 4;
  const int m0 = blockIdx.x * 128;
  const int n0 = blockIdx.y * 128;
  const int sw = (lr >> 1) & 3;

  const f32x4 fzero = {0.f, 0.f, 0.f, 0.f};
  f32x4 acc[4][4];
#pragma unroll
  for (int i = 0; i < 4; i++)
#pragma unroll
    for (int j = 0; j < 4; j++) acc[i][j] = fzero;

  for (int kt = 0; kt < 32; ++kt) {
    const int k0 = kt * 32;
    __syncthreads();
#pragma unroll
    for (int j = 0; j < 2; ++j) {
      const int idx = j * 256 + tid;
      const int row = idx >> 2;
      const int ce = ((idx & 3) ^ ((row >> 1) & 3)) * 8;   // pre-swizzled src
      gload_lds16(X + (size_t)(m0 + row) * 1024 + k0 + ce,
                  (void*)(As + (size_t)(j * 256 + (tid & ~63)) * 8));
      gload_lds16(W + (size_t)(n0 + row) * 1024 + k0 + ce,
                  (void*)(Bs + (size_t)(j * 256 + (tid & ~63)) * 8));
    }
    __syncthreads();
    short8 a[4], b[4];
#pragma unroll
    for (int i = 0; i < 4; i++) a[i] = *(const short8*)(As + (wr * 64 + i * 16 + lr) * 32 + ((lk ^ sw) * 8));
#pragma unroll
    for (int i = 0; i < 4; i++) b[i] = *(const short8*)(Bs + (wc * 64 + i * 16 + lr) * 32 + ((lk ^ sw) * 8));
#pragma unroll
    for (int mf = 0; mf < 4; mf++)
#pragma unroll
      for (int nf = 0; nf < 4; nf++)
        acc[mf][nf] = __builtin_amdgcn_mfma_f32_16x16x32_bf16(a[mf], b[nf], acc[mf][nf], 0, 0, 0);
  }
  const int f = *flag;
#pragma unroll
  for (int mf = 0; mf < 4; mf++)
#pragma unroll
    for (int nf = 0; nf < 4; nf++)
#pragma unroll
      for (int r = 0; r < 4; r++) {
        const int row = m0 + wr * 64 + mf * 16 + lk * 4 + r;
        const int col = n0 + wc * 64 + nf * 16 + lr;
        const size_t oi = (size_t)row * 1024 + col;
        if (f) ((__hip_bfloat16*)out)[oi] = __float2bfloat16(acc[mf][nf][r]);
        else   ((float*)out)[oi] = acc[mf][nf][r];
      }
}

// ---------------- launch ----------------
extern "C" void kernel_launch(void* const* d_in, const int* in_sizes, int n_in,
                              void* d_out, int out_size, void* d_ws, size_t ws_size,
                              hipStream_t stream) {
  const void* x = d_in[0];     // [4,2048,1024]
  const void* wqkv = d_in[1];  // [3072,1024]
  const void* wo = d_in[2];    // [1024,1024]

  char* ws = (char*)d_ws;
  int* flag = (int*)ws;
  __hip_bfloat16* xb    = (__hip_bfloat16*)(ws + 256);
  __hip_bfloat16* wqkvb = xb + 8388608;
  __hip_bfloat16* wob   = wqkvb + 3145728;
  __hip_bfloat16* qws   = wob + 1048576;
  __hip_bfloat16* kws   = qws + 8388608;   // 64*2048*64
  __hip_bfloat16* vtws  = kws + 8388608;
  __hip_bfloat16* yws   = xb;              // alias: xb dead after QKV GEMM
  // peak ws use: ~72 MB

  k_detect<<<1, 256, 0, stream>>>((const unsigned int*)x, flag);
  k_convert3<<<2048, 256, 0, stream>>>(x, wqkv, wo, (unsigned short*)xb, flag);

  dim3 g1(64, 24);
  k_gemm_qkv<<<g1, 256, 0, stream>>>(xb, wqkvb, qws, kws, vtws);

  k_attn<<<512, 512, 0, stream>>>(qws, kws, vtws, yws);

  dim3 g3(64, 8);
  k_gemm_out<<<g3, 256, 0, stream>>>(yws, wob, d_out, flag);
}

// Round 12
// 182.258 us; speedup vs baseline: 2.4125x; 1.0282x over previous
//
#include <hip/hip_runtime.h>
#include <hip/hip_bf16.h>
#include <stdint.h>

// Fused causal attention block: qkv proj -> flash attention -> out proj.
// B=4 T=2048 C=1024 H=16 HD=64.  All MFMA 16x16x32 bf16, fp32 accum.
// Q pre-scaled by 0.125*log2(e); base-2 softmax via raw v_exp_f32; T13.
// attn: T12 swapped-QK^T in-register softmax + 3-buf counted-vmcnt pipeline.
// GEMMs: same 3-buf counted-vmcnt pipeline (R12) + chunk XOR-swizzle.

typedef __attribute__((ext_vector_type(8))) short short8;
typedef __attribute__((ext_vector_type(4))) float f32x4;
typedef __attribute__((ext_vector_type(4))) float float4v;
typedef __attribute__((ext_vector_type(4))) unsigned short ushort4v;
typedef __attribute__((ext_vector_type(4))) unsigned int u32x4;

#define AS1 __attribute__((address_space(1)))
#define AS3 __attribute__((address_space(3)))

#if __has_builtin(__builtin_amdgcn_exp2f)
#define EXP2(x) __builtin_amdgcn_exp2f(x)
#else
#define EXP2(x) __expf((x) * 0.69314718f)
#endif

static __device__ __forceinline__ void gload_lds16(const void* g, void* l) {
  __builtin_amdgcn_global_load_lds((const AS1 void*)g, (AS3 void*)l, 16, 0, 0);
}

// ---------------- dtype detect ----------------
__global__ void k_detect(const unsigned int* __restrict__ x, int* __restrict__ flag) {
  __shared__ int sm[256];
  int c = 0;
  for (int i = 0; i < 8; ++i) {
    unsigned int v = x[threadIdx.x * 8 + i];
    unsigned int e = (v >> 7) & 0xffu;
    if (e >= 110u && e <= 140u) c++;
  }
  sm[threadIdx.x] = c;
  __syncthreads();
  if (threadIdx.x == 0) {
    int t = 0;
    for (int i = 0; i < 256; ++i) t += sm[i];
    *flag = (t > 1024) ? 1 : 0;   // 1 = inputs are bf16, 0 = fp32
  }
}

// ---------------- fused convert: x | wqkv | wo -> contiguous bf16 ws ----------------
__global__ void k_convert3(const void* __restrict__ xs, const void* __restrict__ wqs,
                           const void* __restrict__ wos, unsigned short* __restrict__ out,
                           const int* __restrict__ flag) {
  const int f = *flag;
  const int stride = gridDim.x * blockDim.x;
  for (int v = blockIdx.x * blockDim.x + threadIdx.x; v < 3145728; v += stride) {
    const int i = v * 4;
    const void* src; int j;
    if (i < 8388608)        { src = xs;  j = i; }
    else if (i < 11534336)  { src = wqs; j = i - 8388608; }
    else                    { src = wos; j = i - 11534336; }
    ushort4v r;
    if (f) {
      r = *(const ushort4v*)((const unsigned short*)src + j);
    } else {
      float4v fv = *(const float4v*)((const float*)src + j);
#pragma unroll
      for (int e = 0; e < 4; e++) {
        __hip_bfloat16 h = __float2bfloat16(fv[e]);
        r[e] = *(unsigned short*)&h;
      }
    }
    *(ushort4v*)(out + i) = r;
  }
}

// ---------------- stage 1: QKV GEMM (3-buf counted-vmcnt pipeline) ----------------
// Loop: vmcnt(4) -> s_barrier -> compute(t) -> issue(t+2). 4 loads/thread/
// tile so vmcnt(4) drains exactly tile t, keeps t+1 in flight (no vmcnt(0)
// mid-loop; R11 profile showed the drain-every-tile structure was the
// bottleneck -- T2 swizzle fixed conflicts to 0 with no time change).
// LDS chunk swizzle: position p of row r holds global chunk p ^ ((r>>1)&3).
__global__ __launch_bounds__(256) void k_gemm_qkv(
    const __hip_bfloat16* __restrict__ X, const __hip_bfloat16* __restrict__ W,
    __hip_bfloat16* __restrict__ qo, __hip_bfloat16* __restrict__ ko,
    __hip_bfloat16* __restrict__ vto) {
  __shared__ __align__(16) __hip_bfloat16 As[3][128 * 32];
  __shared__ __align__(16) __hip_bfloat16 Bs[3][128 * 32];
  const int tid = threadIdx.x;
  const int lane = tid & 63;
  const int wid = tid >> 6;
  const int wr = wid >> 1, wc = wid & 1;
  const int lr = lane & 15, lk = lane >> 4;
  const int m0 = blockIdx.x * 128;
  const int n0 = blockIdx.y * 128;
  const int sw = (lr >> 1) & 3;              // lane-uniform s(r) for reads

  // staging geometry (hoisted): 2 chunks per thread per matrix
  const int row0 = tid >> 2,          row1 = (256 + tid) >> 2;
  const int ce0 = ((tid & 3) ^ ((row0 >> 1) & 3)) * 8;
  const int ce1 = ((tid & 3) ^ ((row1 >> 1) & 3)) * 8;
  const int d0 = (tid & ~63) * 8, d1 = (256 + (tid & ~63)) * 8;

  const f32x4 fzero = {0.f, 0.f, 0.f, 0.f};
  f32x4 acc[4][4];
#pragma unroll
  for (int i = 0; i < 4; i++)
#pragma unroll
    for (int j = 0; j < 4; j++) acc[i][j] = fzero;

#define QKV_STAGE(buf, kt2)                                                     \
  {                                                                             \
    const int kk = (kt2) * 32;                                                  \
    gload_lds16(X + (size_t)(m0 + row0) * 1024 + kk + ce0, (void*)(As[buf] + d0)); \
    gload_lds16(W + (size_t)(n0 + row0) * 1024 + kk + ce0, (void*)(Bs[buf] + d0)); \
    gload_lds16(X + (size_t)(m0 + row1) * 1024 + kk + ce1, (void*)(As[buf] + d1)); \
    gload_lds16(W + (size_t)(n0 + row1) * 1024 + kk + ce1, (void*)(Bs[buf] + d1)); \
  }

  QKV_STAGE(0, 0)
  QKV_STAGE(1, 1)

  int cur = 0;
  for (int kt = 0; kt < 32; ++kt) {
    if (kt + 1 < 32) { asm volatile("s_waitcnt vmcnt(4)" ::: "memory"); }
    else             { asm volatile("s_waitcnt vmcnt(0)" ::: "memory"); }
    __builtin_amdgcn_s_barrier();
    __builtin_amdgcn_sched_barrier(0);

    short8 a[4], b[4];
#pragma unroll
    for (int i = 0; i < 4; i++) a[i] = *(const short8*)(As[cur] + (wr * 64 + i * 16 + lr) * 32 + ((lk ^ sw) * 8));
#pragma unroll
    for (int i = 0; i < 4; i++) b[i] = *(const short8*)(Bs[cur] + (wc * 64 + i * 16 + lr) * 32 + ((lk ^ sw) * 8));
#pragma unroll
    for (int mf = 0; mf < 4; mf++)
#pragma unroll
      for (int nf = 0; nf < 4; nf++)
        acc[mf][nf] = __builtin_amdgcn_mfma_f32_16x16x32_bf16(a[mf], b[nf], acc[mf][nf], 0, 0, 0);

    if (kt + 2 < 32) {
      int tb = cur + 2; if (tb >= 3) tb -= 3;
      QKV_STAGE(tb, kt + 2)
    }
    cur = (cur + 1 == 3) ? 0 : cur + 1;
  }
#undef QKV_STAGE

#pragma unroll
  for (int mf = 0; mf < 4; mf++)
#pragma unroll
    for (int nf = 0; nf < 4; nf++)
#pragma unroll
      for (int r = 0; r < 4; r++) {
        const int row = m0 + wr * 64 + mf * 16 + lk * 4 + r;  // b*T+t
        const int col = n0 + wc * 64 + nf * 16 + lr;          // [0,3072)
        const int s = col >> 10;
        const int rem = col & 1023;
        const int h = rem >> 6, hd = rem & 63;
        const int bb = row >> 11, t = row & 2047;
        const size_t bh = (size_t)(bb * 16 + h);
        if (s == 0) {
          // pre-scale Q by 0.125 * log2(e): softmax runs in base-2 domain
          qo[(bh * 2048 + t) * 64 + hd] = __float2bfloat16(acc[mf][nf][r] * 0.18033688f);
        } else if (s == 1) {
          ko[(bh * 2048 + t) * 64 + hd] = __float2bfloat16(acc[mf][nf][r]);
        } else {
          vto[(bh * 64 + hd) * 2048 + t] = __float2bfloat16(acc[mf][nf][r]);
        }
      }
}

// ---------------- stage 2: flash attention (T12 swapped QK^T) ----------------
// 512 blocks x 512 threads (8 waves). Q-tile 256 rows (32/wave). KV tile 64.
// bh = bid&63, p = bid>>6 mapped so CU pairs (e,7-e) have equal totals.
// 3 LDS KV buffers, issue 2 ahead, counted vmcnt(2).
// Swapped QK^T: C = mfma(A=K, B=Q) -> lane owns one q (col=lr), 16 k's.
// A-row permutation f(a,i) = (i>>2)*8 + (a&1)*4 + (i&3) + (a>>1)*32 makes
// lane lk's C regs = exactly k = {lk*8..+7} (+32) -> PV B-frag is built
// IN-LANE (no LDS P, no cross-lane moves). Softmax: 2 shfl per q-group
// (max only); l-sum deferred per-lane to epilogue. O comes out transposed
// -> LDS transpose epilogue (bank-XOR'd) -> coalesced 16B Y stores.
// LDS swizzle F(r) = (r&7) ^ (2*(r>>3) & 7) keeps kb/vb reads uniform.
__global__ __launch_bounds__(512) void k_attn(
    const __hip_bfloat16* __restrict__ Q, const __hip_bfloat16* __restrict__ K,
    const __hip_bfloat16* __restrict__ VT, __hip_bfloat16* __restrict__ Y) {
  __shared__ __align__(16) char smem[49152];   // K bufs 0..2 | V bufs 0..2
  char* smc = smem;
  const int tid = threadIdx.x, lane = tid & 63, wid = tid >> 6;
  const int lr = lane & 15, lk = lane >> 4;

  const int bid = blockIdx.x;
  const int bh = bid & 63;
  const int p = bid >> 6;            // 0..7
  const int e = p & 3;
  const int x = (p < 4) ? p : 7 - e; // CU gets {e, 7-e}: 36 tiles total
  const int q0 = x * 256;
  const int qb = q0 + wid * 32;
  const size_t base = (size_t)bh * 2048 * 64;

  // staging: 512 chunks of 16B per 64x64 tile, source pre-swizzled by F
  const int srow = tid >> 3;                        // 0..63
  const int fs = (srow & 7) ^ ((2 * (srow >> 3)) & 7);
  const int scol = ((tid & 7) ^ fs) * 8;
  const __hip_bfloat16* kg = K + base + scol;
  const __hip_bfloat16* vg = VT + base + (size_t)srow * 2048 + scol;
  const int ldst = (tid & ~63) * 16;                // wave-uniform LDS dest

  // per-lane read offsets (bytes within an 8KB buffer)
  int koff[4][2], voff[4][2], kla[4];
#pragma unroll
  for (int a = 0; a < 4; a++) {
    const int ra = (lr >> 2) * 8 + (a & 1) * 4 + (lr & 3) + (a >> 1) * 32;
    const int fr = (ra & 7) ^ ((2 * (ra >> 3)) & 7);
    kla[a] = lk * 8 + (a & 1) * 4 + (a >> 1) * 32;
#pragma unroll
    for (int ks = 0; ks < 2; ks++)
      koff[a][ks] = ra * 128 + (((ks * 4 + lk) ^ fr) * 16);
  }
#pragma unroll
  for (int df = 0; df < 4; df++) {
    const int rv = df * 16 + lr;
    const int fv = (rv & 7) ^ ((2 * (rv >> 3)) & 7);
#pragma unroll
    for (int ks = 0; ks < 2; ks++)
      voff[df][ks] = rv * 128 + (((ks * 4 + lk) ^ fv) * 16);
  }

  short8 qf[2][2];
#pragma unroll
  for (int qg = 0; qg < 2; qg++)
#pragma unroll
    for (int ks = 0; ks < 2; ks++)
      qf[qg][ks] = *(const short8*)(Q + base + (size_t)(qb + qg * 16 + lr) * 64 + ks * 32 + lk * 8);

  const f32x4 fzero = {0.f, 0.f, 0.f, 0.f};
  f32x4 ot[2][4];                     // O^T accum: row d, col q
  float mrow[2] = {-1e30f, -1e30f}, lrow[2] = {0.f, 0.f};
#pragma unroll
  for (int qg = 0; qg < 2; qg++)
#pragma unroll
    for (int df = 0; df < 4; df++) ot[qg][df] = fzero;

  const int nkv = x * 4 + 4;
  // prologue: stage tiles 0,1 into bufs 0,1
  gload_lds16(kg + (size_t)srow * 64, (void*)(smc + ldst));
  gload_lds16(vg, (void*)(smc + 24576 + ldst));
  gload_lds16(kg + (size_t)(64 + srow) * 64, (void*)(smc + 8192 + ldst));
  gload_lds16(vg + 64, (void*)(smc + 24576 + 8192 + ldst));

  int cur = 0;
  for (int kt = 0; kt < nkv; ++kt) {
    const int k0 = kt * 64;
    if (kt + 1 < nkv) { asm volatile("s_waitcnt vmcnt(2)" ::: "memory"); }
    else              { asm volatile("s_waitcnt vmcnt(0)" ::: "memory"); }
    __builtin_amdgcn_s_barrier();
    __builtin_amdgcn_sched_barrier(0);

    if (k0 <= qb + 31) {   // wave-uniform: skip fully-masked tiles
      const char* kbuf = smc + cur * 8192;
      const char* vbuf = smc + 24576 + cur * 8192;

      f32x4 s[2][4];
#pragma unroll
      for (int qg = 0; qg < 2; qg++)
#pragma unroll
        for (int a = 0; a < 4; a++) s[qg][a] = fzero;

      __builtin_amdgcn_s_setprio(1);
#pragma unroll
      for (int ks = 0; ks < 2; ks++)
#pragma unroll
        for (int a = 0; a < 4; a++) {
          const short8 kb = *(const short8*)(kbuf + koff[a][ks]);
          s[0][a] = __builtin_amdgcn_mfma_f32_16x16x32_bf16(kb, qf[0][ks], s[0][a], 0, 0, 0);
          s[1][a] = __builtin_amdgcn_mfma_f32_16x16x32_bf16(kb, qf[1][ks], s[1][a], 0, 0, 0);
        }
      __builtin_amdgcn_s_setprio(0);

      const bool needmask = (k0 + 63 > qb);
      short8 pb[2][2];

#pragma unroll
      for (int qg = 0; qg < 2; qg++) {
        const int qq = qb + qg * 16 + lr;
        if (needmask) {
#pragma unroll
          for (int a = 0; a < 4; a++)
#pragma unroll
            for (int r = 0; r < 4; r++)
              if (k0 + kla[a] + r > qq) s[qg][a][r] = -1e30f;
        }
        // in-lane max over 16, then 2 shfl across lk groups
        f32x4 m4;
#pragma unroll
        for (int r = 0; r < 4; r++)
          m4[r] = fmaxf(fmaxf(s[qg][0][r], s[qg][1][r]), fmaxf(s[qg][2][r], s[qg][3][r]));
        float mx = fmaxf(fmaxf(m4[0], m4[1]), fmaxf(m4[2], m4[3]));
        mx = fmaxf(mx, __shfl_xor(mx, 16, 64));
        mx = fmaxf(mx, __shfl_xor(mx, 32, 64));
        const float mold = mrow[qg];
        float m;
        if (__all(mx - mold <= 8.f)) {
          m = mold;            // T13 defer: P bounded by 2^8
        } else {
          m = fmaxf(mold, mx);
          const float alpha = EXP2(mold - m);
          lrow[qg] *= alpha;
          mrow[qg] = m;
#pragma unroll
          for (int df = 0; df < 4; df++) ot[qg][df] *= alpha;
        }
        float rs = 0.f;
#pragma unroll
        for (int a = 0; a < 4; a++)
#pragma unroll
          for (int r = 0; r < 4; r++) {
            const float pv = EXP2(s[qg][a][r] - m);
            s[qg][a][r] = pv;
            rs += pv;
          }
        lrow[qg] += rs;        // per-lane partial; cross-lane at epilogue
        // pack PV B-frags: e<4 from block 2ksP, e>=4 from 2ksP+1 (in-lane!)
#pragma unroll
        for (int ksP = 0; ksP < 2; ksP++) {
          short8 w;
#pragma unroll
          for (int ee = 0; ee < 4; ee++) {
            __hip_bfloat16 h0 = __float2bfloat16(s[qg][2 * ksP][ee]);
            __hip_bfloat16 h1 = __float2bfloat16(s[qg][2 * ksP + 1][ee]);
            w[ee] = *(short*)&h0;
            w[4 + ee] = *(short*)&h1;
          }
          pb[qg][ksP] = w;
        }
      }

      // PV: o^T[d][q] += V^T[d][k] * P[k][q]
      __builtin_amdgcn_s_setprio(1);
#pragma unroll
      for (int ks = 0; ks < 2; ks++)
#pragma unroll
        for (int df = 0; df < 4; df++) {
          const short8 vb = *(const short8*)(vbuf + voff[df][ks]);
          ot[0][df] = __builtin_amdgcn_mfma_f32_16x16x32_bf16(vb, pb[0][ks], ot[0][df], 0, 0, 0);
          ot[1][df] = __builtin_amdgcn_mfma_f32_16x16x32_bf16(vb, pb[1][ks], ot[1][df], 0, 0, 0);
        }
      __builtin_amdgcn_s_setprio(0);
    }

    // issue tile kt+2 into buf (cur+2)%3 AFTER compute (3-buf race-freedom)
    if (kt + 2 < nkv) {
      const int kn = (kt + 2) * 64;
      int tb = cur + 2; if (tb >= 3) tb -= 3;
      gload_lds16(kg + (size_t)(kn + srow) * 64, (void*)(smc + tb * 8192 + ldst));
      gload_lds16(vg + kn, (void*)(smc + 24576 + tb * 8192 + ldst));
    }
    cur = (cur + 1 == 3) ? 0 : cur + 1;
  }

  // ---- epilogue: normalize, transpose through LDS, coalesced store ----
  __syncthreads();                      // all waves done with K/V buffers
  unsigned int* Os = (unsigned int*)smc; // 256 rows x 32 u32 = 32 KB
#pragma unroll
  for (int qg = 0; qg < 2; qg++) {
    float ls = lrow[qg];
    ls += __shfl_xor(ls, 16, 64);
    ls += __shfl_xor(ls, 32, 64);
    const float inv = 1.f / ls;
    const int qlocal = wid * 32 + qg * 16 + lr;
    const int sw = (lr & 7) << 2;
#pragma unroll
    for (int df = 0; df < 4; df++)
#pragma unroll
      for (int e2 = 0; e2 < 2; e2++) {
        __hip_bfloat16 h0 = __float2bfloat16(ot[qg][df][2 * e2] * inv);
        __hip_bfloat16 h1 = __float2bfloat16(ot[qg][df][2 * e2 + 1] * inv);
        const unsigned int w = (unsigned int)*(unsigned short*)&h0 |
                               ((unsigned int)*(unsigned short*)&h1 << 16);
        Os[qlocal * 32 + ((df * 8 + lk * 2 + e2) ^ sw)] = w;
      }
  }
  __syncthreads();
  {
    const int qrow = tid >> 1, half = tid & 1, q7 = qrow & 7;
    const int b = bh >> 4, h = bh & 15;
    unsigned int* Yu = (unsigned int*)Y;
    const size_t rowbase = ((size_t)b * 2048 + q0 + qrow) * 512 + h * 32;
#pragma unroll
    for (int g = 0; g < 4; g++) {
      const int cg = half * 4 + g;
      const u32x4 v = *(const u32x4*)(smc + qrow * 128 + ((cg ^ q7) * 16));
      *(u32x4*)(Yu + rowbase + cg * 4) = v;
    }
  }
}

// ---------------- stage 3: output GEMM (3-buf counted-vmcnt pipeline) ----------------
__global__ __launch_bounds__(256) void k_gemm_out(
    const __hip_bfloat16* __restrict__ X, const __hip_bfloat16* __restrict__ W,
    void* __restrict__ out, const int* __restrict__ flag) {
  __shared__ __align__(16) __hip_bfloat16 As[3][128 * 32];
  __shared__ __align__(16) __hip_bfloat16 Bs[3][128 * 32];
  const int tid = threadIdx.x;
  const int lane = tid & 63;
  const int wid = tid >> 6;
  const int wr = wid >> 1, wc = wid & 1;
  const int lr = lane & 15, lk = lane >> 4;
  const int m0 = blockIdx.x * 128;
  const int n0 = blockIdx.y * 128;
  const int sw = (lr >> 1) & 3;

  const int row0 = tid >> 2,          row1 = (256 + tid) >> 2;
  const int ce0 = ((tid & 3) ^ ((row0 >> 1) & 3)) * 8;
  const int ce1 = ((tid & 3) ^ ((row1 >> 1) & 3)) * 8;
  const int d0 = (tid & ~63) * 8, d1 = (256 + (tid & ~63)) * 8;

  const f32x4 fzero = {0.f, 0.f, 0.f, 0.f};
  f32x4 acc[4][4];
#pragma unroll
  for (int i = 0; i < 4; i++)
#pragma unroll
    for (int j = 0; j < 4; j++) acc[i][j] = fzero;

#define OUT_STAGE(buf, kt2)                                                     \
  {                                                                             \
    const int kk = (kt2) * 32;                                                  \
    gload_lds16(X + (size_t)(m0 + row0) * 1024 + kk + ce0, (void*)(As[buf] + d0)); \
    gload_lds16(W + (size_t)(n0 + row0) * 1024 + kk + ce0, (void*)(Bs[buf] + d0)); \
    gload_lds16(X + (size_t)(m0 + row1) * 1024 + kk + ce1, (void*)(As[buf] + d1)); \
    gload_lds16(W + (size_t)(n0 + row1) * 1024 + kk + ce1, (void*)(Bs[buf] + d1)); \
  }

  OUT_STAGE(0, 0)
  OUT_STAGE(1, 1)

  int cur = 0;
  for (int kt = 0; kt < 32; ++kt) {
    if (kt + 1 < 32) { asm volatile("s_waitcnt vmcnt(4)" ::: "memory"); }
    else             { asm volatile("s_waitcnt vmcnt(0)" ::: "memory"); }
    __builtin_amdgcn_s_barrier();
    __builtin_amdgcn_sched_barrier(0);

    short8 a[4], b[4];
#pragma unroll
    for (int i = 0; i < 4; i++) a[i] = *(const short8*)(As[cur] + (wr * 64 + i * 16 + lr) * 32 + ((lk ^ sw) * 8));
#pragma unroll
    for (int i = 0; i < 4; i++) b[i] = *(const short8*)(Bs[cur] + (wc * 64 + i * 16 + lr) * 32 + ((lk ^ sw) * 8));
#pragma unroll
    for (int mf = 0; mf < 4; mf++)
#pragma unroll
      for (int nf = 0; nf < 4; nf++)
        acc[mf][nf] = __builtin_amdgcn_mfma_f32_16x16x32_bf16(a[mf], b[nf], acc[mf][nf], 0, 0, 0);

    if (kt + 2 < 32) {
      int tb = cur + 2; if (tb >= 3) tb -= 3;
      OUT_STAGE(tb, kt + 2)
    }
    cur = (cur + 1 == 3) ? 0 : cur + 1;
  }
#undef OUT_STAGE

  const int f = *flag;
#pragma unroll
  for (int mf = 0; mf < 4; mf++)
#pragma unroll
    for (int nf = 0; nf < 4; nf++)
#pragma unroll
      for (int r = 0; r < 4; r++) {
        const int row = m0 + wr * 64 + mf * 16 + lk * 4 + r;
        const int col = n0 + wc * 64 + nf * 16 + lr;
        const size_t oi = (size_t)row * 1024 + col;
        if (f) ((__hip_bfloat16*)out)[oi] = __float2bfloat16(acc[mf][nf][r]);
        else   ((float*)out)[oi] = acc[mf][nf][r];
      }
}

// ---------------- launch ----------------
extern "C" void kernel_launch(void* const* d_in, const int* in_sizes, int n_in,
                              void* d_out, int out_size, void* d_ws, size_t ws_size,
                              hipStream_t stream) {
  const void* x = d_in[0];     // [4,2048,1024]
  const void* wqkv = d_in[1];  // [3072,1024]
  const void* wo = d_in[2];    // [1024,1024]

  char* ws = (char*)d_ws;
  int* flag = (int*)ws;
  __hip_bfloat16* xb    = (__hip_bfloat16*)(ws + 256);
  __hip_bfloat16* wqkvb = xb + 8388608;
  __hip_bfloat16* wob   = wqkvb + 3145728;
  __hip_bfloat16* qws   = wob + 1048576;
  __hip_bfloat16* kws   = qws + 8388608;   // 64*2048*64
  __hip_bfloat16* vtws  = kws + 8388608;
  __hip_bfloat16* yws   = xb;              // alias: xb dead after QKV GEMM
  // peak ws use: ~72 MB

  k_detect<<<1, 256, 0, stream>>>((const unsigned int*)x, flag);
  k_convert3<<<2048, 256, 0, stream>>>(x, wqkv, wo, (unsigned short*)xb, flag);

  dim3 g1(64, 24);
  k_gemm_qkv<<<g1, 256, 0, stream>>>(xb, wqkvb, qws, kws, vtws);

  k_attn<<<512, 512, 0, stream>>>(qws, kws, vtws, yws);

  dim3 g3(64, 8);
  k_gemm_out<<<g3, 256, 0, stream>>>(yws, wob, d_out, flag);
}

// Round 13
// 180.731 us; speedup vs baseline: 2.4329x; 1.0084x over previous
//
#include <hip/hip_runtime.h>
#include <hip/hip_bf16.h>
#include <stdint.h>

// Fused causal attention block: qkv proj -> flash attention -> out proj.
// B=4 T=2048 C=1024 H=16 HD=64.  All MFMA 16x16x32 bf16, fp32 accum.
// Q pre-scaled by 0.125*log2(e); base-2 softmax via raw v_exp_f32; T13.
// attn: T12 swapped-QK^T in-register softmax + 3-buf counted-vmcnt pipeline.
// GEMMs (R13): 8-wave 128^2 blocks (wave tile 32x64) -- R12 profile showed
// TLP starvation (2 waves/SIMD, ~2175cy/K-step vs ~500cy work).

typedef __attribute__((ext_vector_type(8))) short short8;
typedef __attribute__((ext_vector_type(4))) float f32x4;
typedef __attribute__((ext_vector_type(4))) float float4v;
typedef __attribute__((ext_vector_type(4))) unsigned short ushort4v;
typedef __attribute__((ext_vector_type(4))) unsigned int u32x4;

#define AS1 __attribute__((address_space(1)))
#define AS3 __attribute__((address_space(3)))

#if __has_builtin(__builtin_amdgcn_exp2f)
#define EXP2(x) __builtin_amdgcn_exp2f(x)
#else
#define EXP2(x) __expf((x) * 0.69314718f)
#endif

static __device__ __forceinline__ void gload_lds16(const void* g, void* l) {
  __builtin_amdgcn_global_load_lds((const AS1 void*)g, (AS3 void*)l, 16, 0, 0);
}

// ---------------- dtype detect ----------------
__global__ void k_detect(const unsigned int* __restrict__ x, int* __restrict__ flag) {
  __shared__ int sm[256];
  int c = 0;
  for (int i = 0; i < 8; ++i) {
    unsigned int v = x[threadIdx.x * 8 + i];
    unsigned int e = (v >> 7) & 0xffu;
    if (e >= 110u && e <= 140u) c++;
  }
  sm[threadIdx.x] = c;
  __syncthreads();
  if (threadIdx.x == 0) {
    int t = 0;
    for (int i = 0; i < 256; ++i) t += sm[i];
    *flag = (t > 1024) ? 1 : 0;   // 1 = inputs are bf16, 0 = fp32
  }
}

// ---------------- fused convert: x | wqkv | wo -> contiguous bf16 ws ----------------
__global__ void k_convert3(const void* __restrict__ xs, const void* __restrict__ wqs,
                           const void* __restrict__ wos, unsigned short* __restrict__ out,
                           const int* __restrict__ flag) {
  const int f = *flag;
  const int stride = gridDim.x * blockDim.x;
  for (int v = blockIdx.x * blockDim.x + threadIdx.x; v < 3145728; v += stride) {
    const int i = v * 4;
    const void* src; int j;
    if (i < 8388608)        { src = xs;  j = i; }
    else if (i < 11534336)  { src = wqs; j = i - 8388608; }
    else                    { src = wos; j = i - 11534336; }
    ushort4v r;
    if (f) {
      r = *(const ushort4v*)((const unsigned short*)src + j);
    } else {
      float4v fv = *(const float4v*)((const float*)src + j);
#pragma unroll
      for (int e = 0; e < 4; e++) {
        __hip_bfloat16 h = __float2bfloat16(fv[e]);
        r[e] = *(unsigned short*)&h;
      }
    }
    *(ushort4v*)(out + i) = r;
  }
}

// ---------------- stage 1: QKV GEMM (8 waves, 3-buf counted vmcnt) ----------------
// 512 threads, wave tile 32x64 (wr=wid&3 m-block, wc=wid>>2 n-block).
// 1 chunk/thread/matrix staging -> 2 gload_lds/tile -> vmcnt(2) (attn-proven).
// LDS chunk swizzle: position p of row r holds global chunk p ^ ((r>>1)&3).
__global__ __launch_bounds__(512) void k_gemm_qkv(
    const __hip_bfloat16* __restrict__ X, const __hip_bfloat16* __restrict__ W,
    __hip_bfloat16* __restrict__ qo, __hip_bfloat16* __restrict__ ko,
    __hip_bfloat16* __restrict__ vto) {
  __shared__ __align__(16) __hip_bfloat16 As[3][128 * 32];
  __shared__ __align__(16) __hip_bfloat16 Bs[3][128 * 32];
  const int tid = threadIdx.x;
  const int lane = tid & 63;
  const int wid = tid >> 6;
  const int wr = wid & 3, wc = wid >> 2;
  const int lr = lane & 15, lk = lane >> 4;
  const int m0 = blockIdx.x * 128;
  const int n0 = blockIdx.y * 128;
  const int sw = (lr >> 1) & 3;              // lane-uniform s(r) for reads

  // staging geometry: 512 chunks of 16B per 128x32 tile, 1/thread/matrix
  const int row = tid >> 2;
  const int ce = ((tid & 3) ^ ((row >> 1) & 3)) * 8;
  const int dst = (tid & ~63) * 8;

  const f32x4 fzero = {0.f, 0.f, 0.f, 0.f};
  f32x4 acc[2][4];
#pragma unroll
  for (int i = 0; i < 2; i++)
#pragma unroll
    for (int j = 0; j < 4; j++) acc[i][j] = fzero;

#define QKV_STAGE(buf, kt2)                                                        \
  {                                                                                \
    const int kk = (kt2) * 32;                                                     \
    gload_lds16(X + (size_t)(m0 + row) * 1024 + kk + ce, (void*)(As[buf] + dst));  \
    gload_lds16(W + (size_t)(n0 + row) * 1024 + kk + ce, (void*)(Bs[buf] + dst));  \
  }

  QKV_STAGE(0, 0)
  QKV_STAGE(1, 1)

  int cur = 0;
  for (int kt = 0; kt < 32; ++kt) {
    if (kt + 1 < 32) { asm volatile("s_waitcnt vmcnt(2)" ::: "memory"); }
    else             { asm volatile("s_waitcnt vmcnt(0)" ::: "memory"); }
    __builtin_amdgcn_s_barrier();
    __builtin_amdgcn_sched_barrier(0);

    short8 a[2], b[4];
#pragma unroll
    for (int i = 0; i < 2; i++) a[i] = *(const short8*)(As[cur] + (wr * 32 + i * 16 + lr) * 32 + ((lk ^ sw) * 8));
#pragma unroll
    for (int i = 0; i < 4; i++) b[i] = *(const short8*)(Bs[cur] + (wc * 64 + i * 16 + lr) * 32 + ((lk ^ sw) * 8));
#pragma unroll
    for (int mf = 0; mf < 2; mf++)
#pragma unroll
      for (int nf = 0; nf < 4; nf++)
        acc[mf][nf] = __builtin_amdgcn_mfma_f32_16x16x32_bf16(a[mf], b[nf], acc[mf][nf], 0, 0, 0);

    if (kt + 2 < 32) {
      int tb = cur + 2; if (tb >= 3) tb -= 3;
      QKV_STAGE(tb, kt + 2)
    }
    cur = (cur + 1 == 3) ? 0 : cur + 1;
  }
#undef QKV_STAGE

#pragma unroll
  for (int mf = 0; mf < 2; mf++)
#pragma unroll
    for (int nf = 0; nf < 4; nf++)
#pragma unroll
      for (int r = 0; r < 4; r++) {
        const int orow = m0 + wr * 32 + mf * 16 + lk * 4 + r;  // b*T+t
        const int col = n0 + wc * 64 + nf * 16 + lr;           // [0,3072)
        const int s = col >> 10;
        const int rem = col & 1023;
        const int h = rem >> 6, hd = rem & 63;
        const int bb = orow >> 11, t = orow & 2047;
        const size_t bh = (size_t)(bb * 16 + h);
        if (s == 0) {
          // pre-scale Q by 0.125 * log2(e): softmax runs in base-2 domain
          qo[(bh * 2048 + t) * 64 + hd] = __float2bfloat16(acc[mf][nf][r] * 0.18033688f);
        } else if (s == 1) {
          ko[(bh * 2048 + t) * 64 + hd] = __float2bfloat16(acc[mf][nf][r]);
        } else {
          vto[(bh * 64 + hd) * 2048 + t] = __float2bfloat16(acc[mf][nf][r]);
        }
      }
}

// ---------------- stage 2: flash attention (T12 swapped QK^T) ----------------
// 512 blocks x 512 threads (8 waves). Q-tile 256 rows (32/wave). KV tile 64.
// bh = bid&63, p = bid>>6 mapped so CU pairs (e,7-e) have equal totals.
// 3 LDS KV buffers, issue 2 ahead, counted vmcnt(2).
// Swapped QK^T: C = mfma(A=K, B=Q) -> lane owns one q (col=lr), 16 k's.
// A-row permutation f(a,i) = (i>>2)*8 + (a&1)*4 + (i&3) + (a>>1)*32 makes
// lane lk's C regs = exactly k = {lk*8..+7} (+32) -> PV B-frag is built
// IN-LANE (no LDS P, no cross-lane moves). Softmax: 2 shfl per q-group
// (max only); l-sum deferred per-lane to epilogue. O comes out transposed
// -> LDS transpose epilogue (bank-XOR'd) -> coalesced 16B Y stores.
// LDS swizzle F(r) = (r&7) ^ (2*(r>>3) & 7) keeps kb/vb reads uniform.
__global__ __launch_bounds__(512) void k_attn(
    const __hip_bfloat16* __restrict__ Q, const __hip_bfloat16* __restrict__ K,
    const __hip_bfloat16* __restrict__ VT, __hip_bfloat16* __restrict__ Y) {
  __shared__ __align__(16) char smem[49152];   // K bufs 0..2 | V bufs 0..2
  char* smc = smem;
  const int tid = threadIdx.x, lane = tid & 63, wid = tid >> 6;
  const int lr = lane & 15, lk = lane >> 4;

  const int bid = blockIdx.x;
  const int bh = bid & 63;
  const int p = bid >> 6;            // 0..7
  const int e = p & 3;
  const int x = (p < 4) ? p : 7 - e; // CU gets {e, 7-e}: 36 tiles total
  const int q0 = x * 256;
  const int qb = q0 + wid * 32;
  const size_t base = (size_t)bh * 2048 * 64;

  // staging: 512 chunks of 16B per 64x64 tile, source pre-swizzled by F
  const int srow = tid >> 3;                        // 0..63
  const int fs = (srow & 7) ^ ((2 * (srow >> 3)) & 7);
  const int scol = ((tid & 7) ^ fs) * 8;
  const __hip_bfloat16* kg = K + base + scol;
  const __hip_bfloat16* vg = VT + base + (size_t)srow * 2048 + scol;
  const int ldst = (tid & ~63) * 16;                // wave-uniform LDS dest

  // per-lane read offsets (bytes within an 8KB buffer)
  int koff[4][2], voff[4][2], kla[4];
#pragma unroll
  for (int a = 0; a < 4; a++) {
    const int ra = (lr >> 2) * 8 + (a & 1) * 4 + (lr & 3) + (a >> 1) * 32;
    const int fr = (ra & 7) ^ ((2 * (ra >> 3)) & 7);
    kla[a] = lk * 8 + (a & 1) * 4 + (a >> 1) * 32;
#pragma unroll
    for (int ks = 0; ks < 2; ks++)
      koff[a][ks] = ra * 128 + (((ks * 4 + lk) ^ fr) * 16);
  }
#pragma unroll
  for (int df = 0; df < 4; df++) {
    const int rv = df * 16 + lr;
    const int fv = (rv & 7) ^ ((2 * (rv >> 3)) & 7);
#pragma unroll
    for (int ks = 0; ks < 2; ks++)
      voff[df][ks] = rv * 128 + (((ks * 4 + lk) ^ fv) * 16);
  }

  short8 qf[2][2];
#pragma unroll
  for (int qg = 0; qg < 2; qg++)
#pragma unroll
    for (int ks = 0; ks < 2; ks++)
      qf[qg][ks] = *(const short8*)(Q + base + (size_t)(qb + qg * 16 + lr) * 64 + ks * 32 + lk * 8);

  const f32x4 fzero = {0.f, 0.f, 0.f, 0.f};
  f32x4 ot[2][4];                     // O^T accum: row d, col q
  float mrow[2] = {-1e30f, -1e30f}, lrow[2] = {0.f, 0.f};
#pragma unroll
  for (int qg = 0; qg < 2; qg++)
#pragma unroll
    for (int df = 0; df < 4; df++) ot[qg][df] = fzero;

  const int nkv = x * 4 + 4;
  // prologue: stage tiles 0,1 into bufs 0,1
  gload_lds16(kg + (size_t)srow * 64, (void*)(smc + ldst));
  gload_lds16(vg, (void*)(smc + 24576 + ldst));
  gload_lds16(kg + (size_t)(64 + srow) * 64, (void*)(smc + 8192 + ldst));
  gload_lds16(vg + 64, (void*)(smc + 24576 + 8192 + ldst));

  int cur = 0;
  for (int kt = 0; kt < nkv; ++kt) {
    const int k0 = kt * 64;
    if (kt + 1 < nkv) { asm volatile("s_waitcnt vmcnt(2)" ::: "memory"); }
    else              { asm volatile("s_waitcnt vmcnt(0)" ::: "memory"); }
    __builtin_amdgcn_s_barrier();
    __builtin_amdgcn_sched_barrier(0);

    if (k0 <= qb + 31) {   // wave-uniform: skip fully-masked tiles
      const char* kbuf = smc + cur * 8192;
      const char* vbuf = smc + 24576 + cur * 8192;

      f32x4 s[2][4];
#pragma unroll
      for (int qg = 0; qg < 2; qg++)
#pragma unroll
        for (int a = 0; a < 4; a++) s[qg][a] = fzero;

      __builtin_amdgcn_s_setprio(1);
#pragma unroll
      for (int ks = 0; ks < 2; ks++)
#pragma unroll
        for (int a = 0; a < 4; a++) {
          const short8 kb = *(const short8*)(kbuf + koff[a][ks]);
          s[0][a] = __builtin_amdgcn_mfma_f32_16x16x32_bf16(kb, qf[0][ks], s[0][a], 0, 0, 0);
          s[1][a] = __builtin_amdgcn_mfma_f32_16x16x32_bf16(kb, qf[1][ks], s[1][a], 0, 0, 0);
        }
      __builtin_amdgcn_s_setprio(0);

      const bool needmask = (k0 + 63 > qb);
      short8 pb[2][2];

#pragma unroll
      for (int qg = 0; qg < 2; qg++) {
        const int qq = qb + qg * 16 + lr;
        if (needmask) {
#pragma unroll
          for (int a = 0; a < 4; a++)
#pragma unroll
            for (int r = 0; r < 4; r++)
              if (k0 + kla[a] + r > qq) s[qg][a][r] = -1e30f;
        }
        // in-lane max over 16, then 2 shfl across lk groups
        f32x4 m4;
#pragma unroll
        for (int r = 0; r < 4; r++)
          m4[r] = fmaxf(fmaxf(s[qg][0][r], s[qg][1][r]), fmaxf(s[qg][2][r], s[qg][3][r]));
        float mx = fmaxf(fmaxf(m4[0], m4[1]), fmaxf(m4[2], m4[3]));
        mx = fmaxf(mx, __shfl_xor(mx, 16, 64));
        mx = fmaxf(mx, __shfl_xor(mx, 32, 64));
        const float mold = mrow[qg];
        float m;
        if (__all(mx - mold <= 8.f)) {
          m = mold;            // T13 defer: P bounded by 2^8
        } else {
          m = fmaxf(mold, mx);
          const float alpha = EXP2(mold - m);
          lrow[qg] *= alpha;
          mrow[qg] = m;
#pragma unroll
          for (int df = 0; df < 4; df++) ot[qg][df] *= alpha;
        }
        float rs = 0.f;
#pragma unroll
        for (int a = 0; a < 4; a++)
#pragma unroll
          for (int r = 0; r < 4; r++) {
            const float pv = EXP2(s[qg][a][r] - m);
            s[qg][a][r] = pv;
            rs += pv;
          }
        lrow[qg] += rs;        // per-lane partial; cross-lane at epilogue
        // pack PV B-frags: e<4 from block 2ksP, e>=4 from 2ksP+1 (in-lane!)
#pragma unroll
        for (int ksP = 0; ksP < 2; ksP++) {
          short8 w;
#pragma unroll
          for (int ee = 0; ee < 4; ee++) {
            __hip_bfloat16 h0 = __float2bfloat16(s[qg][2 * ksP][ee]);
            __hip_bfloat16 h1 = __float2bfloat16(s[qg][2 * ksP + 1][ee]);
            w[ee] = *(short*)&h0;
            w[4 + ee] = *(short*)&h1;
          }
          pb[qg][ksP] = w;
        }
      }

      // PV: o^T[d][q] += V^T[d][k] * P[k][q]
      __builtin_amdgcn_s_setprio(1);
#pragma unroll
      for (int ks = 0; ks < 2; ks++)
#pragma unroll
        for (int df = 0; df < 4; df++) {
          const short8 vb = *(const short8*)(vbuf + voff[df][ks]);
          ot[0][df] = __builtin_amdgcn_mfma_f32_16x16x32_bf16(vb, pb[0][ks], ot[0][df], 0, 0, 0);
          ot[1][df] = __builtin_amdgcn_mfma_f32_16x16x32_bf16(vb, pb[1][ks], ot[1][df], 0, 0, 0);
        }
      __builtin_amdgcn_s_setprio(0);
    }

    // issue tile kt+2 into buf (cur+2)%3 AFTER compute (3-buf race-freedom)
    if (kt + 2 < nkv) {
      const int kn = (kt + 2) * 64;
      int tb = cur + 2; if (tb >= 3) tb -= 3;
      gload_lds16(kg + (size_t)(kn + srow) * 64, (void*)(smc + tb * 8192 + ldst));
      gload_lds16(vg + kn, (void*)(smc + 24576 + tb * 8192 + ldst));
    }
    cur = (cur + 1 == 3) ? 0 : cur + 1;
  }

  // ---- epilogue: normalize, transpose through LDS, coalesced store ----
  __syncthreads();                      // all waves done with K/V buffers
  unsigned int* Os = (unsigned int*)smc; // 256 rows x 32 u32 = 32 KB
#pragma unroll
  for (int qg = 0; qg < 2; qg++) {
    float ls = lrow[qg];
    ls += __shfl_xor(ls, 16, 64);
    ls += __shfl_xor(ls, 32, 64);
    const float inv = 1.f / ls;
    const int qlocal = wid * 32 + qg * 16 + lr;
    const int sw = (lr & 7) << 2;
#pragma unroll
    for (int df = 0; df < 4; df++)
#pragma unroll
      for (int e2 = 0; e2 < 2; e2++) {
        __hip_bfloat16 h0 = __float2bfloat16(ot[qg][df][2 * e2] * inv);
        __hip_bfloat16 h1 = __float2bfloat16(ot[qg][df][2 * e2 + 1] * inv);
        const unsigned int w = (unsigned int)*(unsigned short*)&h0 |
                               ((unsigned int)*(unsigned short*)&h1 << 16);
        Os[qlocal * 32 + ((df * 8 + lk * 2 + e2) ^ sw)] = w;
      }
  }
  __syncthreads();
  {
    const int qrow = tid >> 1, half = tid & 1, q7 = qrow & 7;
    const int b = bh >> 4, h = bh & 15;
    unsigned int* Yu = (unsigned int*)Y;
    const size_t rowbase = ((size_t)b * 2048 + q0 + qrow) * 512 + h * 32;
#pragma unroll
    for (int g = 0; g < 4; g++) {
      const int cg = half * 4 + g;
      const u32x4 v = *(const u32x4*)(smc + qrow * 128 + ((cg ^ q7) * 16));
      *(u32x4*)(Yu + rowbase + cg * 4) = v;
    }
  }
}

// ---------------- stage 3: output GEMM (8 waves, 3-buf counted vmcnt) ----------------
__global__ __launch_bounds__(512) void k_gemm_out(
    const __hip_bfloat16* __restrict__ X, const __hip_bfloat16* __restrict__ W,
    void* __restrict__ out, const int* __restrict__ flag) {
  __shared__ __align__(16) __hip_bfloat16 As[3][128 * 32];
  __shared__ __align__(16) __hip_bfloat16 Bs[3][128 * 32];
  const int tid = threadIdx.x;
  const int lane = tid & 63;
  const int wid = tid >> 6;
  const int wr = wid & 3, wc = wid >> 2;
  const int lr = lane & 15, lk = lane >> 4;
  const int m0 = blockIdx.x * 128;
  const int n0 = blockIdx.y * 128;
  const int sw = (lr >> 1) & 3;

  const int row = tid >> 2;
  const int ce = ((tid & 3) ^ ((row >> 1) & 3)) * 8;
  const int dst = (tid & ~63) * 8;

  const f32x4 fzero = {0.f, 0.f, 0.f, 0.f};
  f32x4 acc[2][4];
#pragma unroll
  for (int i = 0; i < 2; i++)
#pragma unroll
    for (int j = 0; j < 4; j++) acc[i][j] = fzero;

#define OUT_STAGE(buf, kt2)                                                        \
  {                                                                                \
    const int kk = (kt2) * 32;                                                     \
    gload_lds16(X + (size_t)(m0 + row) * 1024 + kk + ce, (void*)(As[buf] + dst));  \
    gload_lds16(W + (size_t)(n0 + row) * 1024 + kk + ce, (void*)(Bs[buf] + dst));  \
  }

  OUT_STAGE(0, 0)
  OUT_STAGE(1, 1)

  int cur = 0;
  for (int kt = 0; kt < 32; ++kt) {
    if (kt + 1 < 32) { asm volatile("s_waitcnt vmcnt(2)" ::: "memory"); }
    else             { asm volatile("s_waitcnt vmcnt(0)" ::: "memory"); }
    __builtin_amdgcn_s_barrier();
    __builtin_amdgcn_sched_barrier(0);

    short8 a[2], b[4];
#pragma unroll
    for (int i = 0; i < 2; i++) a[i] = *(const short8*)(As[cur] + (wr * 32 + i * 16 + lr) * 32 + ((lk ^ sw) * 8));
#pragma unroll
    for (int i = 0; i < 4; i++) b[i] = *(const short8*)(Bs[cur] + (wc * 64 + i * 16 + lr) * 32 + ((lk ^ sw) * 8));
#pragma unroll
    for (int mf = 0; mf < 2; mf++)
#pragma unroll
      for (int nf = 0; nf < 4; nf++)
        acc[mf][nf] = __builtin_amdgcn_mfma_f32_16x16x32_bf16(a[mf], b[nf], acc[mf][nf], 0, 0, 0);

    if (kt + 2 < 32) {
      int tb = cur + 2; if (tb >= 3) tb -= 3;
      OUT_STAGE(tb, kt + 2)
    }
    cur = (cur + 1 == 3) ? 0 : cur + 1;
  }
#undef OUT_STAGE

  const int f = *flag;
#pragma unroll
  for (int mf = 0; mf < 2; mf++)
#pragma unroll
    for (int nf = 0; nf < 4; nf++)
#pragma unroll
      for (int r = 0; r < 4; r++) {
        const int orow = m0 + wr * 32 + mf * 16 + lk * 4 + r;
        const int col = n0 + wc * 64 + nf * 16 + lr;
        const size_t oi = (size_t)orow * 1024 + col;
        if (f) ((__hip_bfloat16*)out)[oi] = __float2bfloat16(acc[mf][nf][r]);
        else   ((float*)out)[oi] = acc[mf][nf][r];
      }
}

// ---------------- launch ----------------
extern "C" void kernel_launch(void* const* d_in, const int* in_sizes, int n_in,
                              void* d_out, int out_size, void* d_ws, size_t ws_size,
                              hipStream_t stream) {
  const void* x = d_in[0];     // [4,2048,1024]
  const void* wqkv = d_in[1];  // [3072,1024]
  const void* wo = d_in[2];    // [1024,1024]

  char* ws = (char*)d_ws;
  int* flag = (int*)ws;
  __hip_bfloat16* xb    = (__hip_bfloat16*)(ws + 256);
  __hip_bfloat16* wqkvb = xb + 8388608;
  __hip_bfloat16* wob   = wqkvb + 3145728;
  __hip_bfloat16* qws   = wob + 1048576;
  __hip_bfloat16* kws   = qws + 8388608;   // 64*2048*64
  __hip_bfloat16* vtws  = kws + 8388608;
  __hip_bfloat16* yws   = xb;              // alias: xb dead after QKV GEMM
  // peak ws use: ~72 MB

  k_detect<<<1, 256, 0, stream>>>((const unsigned int*)x, flag);
  k_convert3<<<2048, 256, 0, stream>>>(x, wqkv, wo, (unsigned short*)xb, flag);

  dim3 g1(64, 24);
  k_gemm_qkv<<<g1, 512, 0, stream>>>(xb, wqkvb, qws, kws, vtws);

  k_attn<<<512, 512, 0, stream>>>(qws, kws, vtws, yws);

  dim3 g3(64, 8);
  k_gemm_out<<<g3, 512, 0, stream>>>(yws, wob, d_out, flag);
}

// Round 14
// 178.881 us; speedup vs baseline: 2.4581x; 1.0103x over previous
//
#include <hip/hip_runtime.h>
#include <hip/hip_bf16.h>
#include <stdint.h>

// Fused causal attention block: qkv proj -> flash attention -> out proj.
// B=4 T=2048 C=1024 H=16 HD=64.  All MFMA 16x16x32 bf16, fp32 accum.
// Q pre-scaled by 0.125*log2(e); base-2 softmax via raw v_exp_f32; T13.
// attn: T12 swapped-QK^T in-register softmax + 3-buf counted-vmcnt pipeline.
// qkv GEMM (R14): 128x256 block tile, wave tile 64x64, 16 MFMA/wave/step
// (R13 showed occupancy 52% but only 8 MFMA per barrier -> overhead-bound).

typedef __attribute__((ext_vector_type(8))) short short8;
typedef __attribute__((ext_vector_type(4))) float f32x4;
typedef __attribute__((ext_vector_type(4))) float float4v;
typedef __attribute__((ext_vector_type(4))) unsigned short ushort4v;
typedef __attribute__((ext_vector_type(4))) unsigned int u32x4;

#define AS1 __attribute__((address_space(1)))
#define AS3 __attribute__((address_space(3)))

#if __has_builtin(__builtin_amdgcn_exp2f)
#define EXP2(x) __builtin_amdgcn_exp2f(x)
#else
#define EXP2(x) __expf((x) * 0.69314718f)
#endif

static __device__ __forceinline__ void gload_lds16(const void* g, void* l) {
  __builtin_amdgcn_global_load_lds((const AS1 void*)g, (AS3 void*)l, 16, 0, 0);
}

// ---------------- dtype detect ----------------
__global__ void k_detect(const unsigned int* __restrict__ x, int* __restrict__ flag) {
  __shared__ int sm[256];
  int c = 0;
  for (int i = 0; i < 8; ++i) {
    unsigned int v = x[threadIdx.x * 8 + i];
    unsigned int e = (v >> 7) & 0xffu;
    if (e >= 110u && e <= 140u) c++;
  }
  sm[threadIdx.x] = c;
  __syncthreads();
  if (threadIdx.x == 0) {
    int t = 0;
    for (int i = 0; i < 256; ++i) t += sm[i];
    *flag = (t > 1024) ? 1 : 0;   // 1 = inputs are bf16, 0 = fp32
  }
}

// ---------------- fused convert: x | wqkv | wo -> contiguous bf16 ws ----------------
__global__ void k_convert3(const void* __restrict__ xs, const void* __restrict__ wqs,
                           const void* __restrict__ wos, unsigned short* __restrict__ out,
                           const int* __restrict__ flag) {
  const int f = *flag;
  const int stride = gridDim.x * blockDim.x;
  for (int v = blockIdx.x * blockDim.x + threadIdx.x; v < 3145728; v += stride) {
    const int i = v * 4;
    const void* src; int j;
    if (i < 8388608)        { src = xs;  j = i; }
    else if (i < 11534336)  { src = wqs; j = i - 8388608; }
    else                    { src = wos; j = i - 11534336; }
    ushort4v r;
    if (f) {
      r = *(const ushort4v*)((const unsigned short*)src + j);
    } else {
      float4v fv = *(const float4v*)((const float*)src + j);
#pragma unroll
      for (int e = 0; e < 4; e++) {
        __hip_bfloat16 h = __float2bfloat16(fv[e]);
        r[e] = *(unsigned short*)&h;
      }
    }
    *(ushort4v*)(out + i) = r;
  }
}

// ---------------- stage 1: QKV GEMM (8 waves, 128x256 tile, 3-buf vmcnt) ----------------
// Wave tile 64x64: wr=wid&1 (m half), wc=wid>>1 (n quarter). 16 MFMA +
// 8 ds_read_b128 per wave per K-step. Staging: A 1 chunk/thread, B 2
// chunks/thread -> 3 gload_lds/tile -> vmcnt(3) steady (2-ahead).
// LDS chunk swizzle: position p of row r holds global chunk p ^ ((r>>1)&3).
__global__ __launch_bounds__(512) void k_gemm_qkv(
    const __hip_bfloat16* __restrict__ X, const __hip_bfloat16* __restrict__ W,
    __hip_bfloat16* __restrict__ qo, __hip_bfloat16* __restrict__ ko,
    __hip_bfloat16* __restrict__ vto) {
  __shared__ __align__(16) __hip_bfloat16 As[3][128 * 32];
  __shared__ __align__(16) __hip_bfloat16 Bs[3][256 * 32];
  const int tid = threadIdx.x;
  const int lane = tid & 63;
  const int wid = tid >> 6;
  const int wr = wid & 1, wc = wid >> 1;
  const int lr = lane & 15, lk = lane >> 4;
  const int m0 = blockIdx.x * 128;
  const int n0 = blockIdx.y * 256;
  const int sw = (lr >> 1) & 3;              // lane-uniform s(r) for reads

  // staging geometry: A 512 chunks (1/thread), B 1024 chunks (2/thread)
  const int rowa = tid >> 2;                 // 0..127
  const int cea = ((tid & 3) ^ ((rowa >> 1) & 3)) * 8;
  const int rowb1 = 128 + rowa;
  const int ceb1 = ((tid & 3) ^ ((rowb1 >> 1) & 3)) * 8;
  const int dsta = (tid & ~63) * 8;
  const int dstb1 = (512 + (tid & ~63)) * 8;

  const f32x4 fzero = {0.f, 0.f, 0.f, 0.f};
  f32x4 acc[4][4];
#pragma unroll
  for (int i = 0; i < 4; i++)
#pragma unroll
    for (int j = 0; j < 4; j++) acc[i][j] = fzero;

#define QKV_STAGE(buf, kt2)                                                          \
  {                                                                                  \
    const int kk = (kt2) * 32;                                                       \
    gload_lds16(X + (size_t)(m0 + rowa) * 1024 + kk + cea, (void*)(As[buf] + dsta)); \
    gload_lds16(W + (size_t)(n0 + rowa) * 1024 + kk + cea, (void*)(Bs[buf] + dsta)); \
    gload_lds16(W + (size_t)(n0 + rowb1) * 1024 + kk + ceb1, (void*)(Bs[buf] + dstb1)); \
  }

  QKV_STAGE(0, 0)
  QKV_STAGE(1, 1)

  int cur = 0;
  for (int kt = 0; kt < 32; ++kt) {
    if (kt + 1 < 32) { asm volatile("s_waitcnt vmcnt(3)" ::: "memory"); }
    else             { asm volatile("s_waitcnt vmcnt(0)" ::: "memory"); }
    __builtin_amdgcn_s_barrier();
    __builtin_amdgcn_sched_barrier(0);

    short8 a[4], b[4];
#pragma unroll
    for (int i = 0; i < 4; i++) a[i] = *(const short8*)(As[cur] + (wr * 64 + i * 16 + lr) * 32 + ((lk ^ sw) * 8));
#pragma unroll
    for (int i = 0; i < 4; i++) b[i] = *(const short8*)(Bs[cur] + (wc * 64 + i * 16 + lr) * 32 + ((lk ^ sw) * 8));
#pragma unroll
    for (int mf = 0; mf < 4; mf++)
#pragma unroll
      for (int nf = 0; nf < 4; nf++)
        acc[mf][nf] = __builtin_amdgcn_mfma_f32_16x16x32_bf16(a[mf], b[nf], acc[mf][nf], 0, 0, 0);

    if (kt + 2 < 32) {
      int tb = cur + 2; if (tb >= 3) tb -= 3;
      QKV_STAGE(tb, kt + 2)
    }
    cur = (cur + 1 == 3) ? 0 : cur + 1;
  }
#undef QKV_STAGE

#pragma unroll
  for (int mf = 0; mf < 4; mf++)
#pragma unroll
    for (int nf = 0; nf < 4; nf++)
#pragma unroll
      for (int r = 0; r < 4; r++) {
        const int orow = m0 + wr * 64 + mf * 16 + lk * 4 + r;  // b*T+t
        const int col = n0 + wc * 64 + nf * 16 + lr;           // [0,3072)
        const int s = col >> 10;
        const int rem = col & 1023;
        const int h = rem >> 6, hd = rem & 63;
        const int bb = orow >> 11, t = orow & 2047;
        const size_t bh = (size_t)(bb * 16 + h);
        if (s == 0) {
          // pre-scale Q by 0.125 * log2(e): softmax runs in base-2 domain
          qo[(bh * 2048 + t) * 64 + hd] = __float2bfloat16(acc[mf][nf][r] * 0.18033688f);
        } else if (s == 1) {
          ko[(bh * 2048 + t) * 64 + hd] = __float2bfloat16(acc[mf][nf][r]);
        } else {
          vto[(bh * 64 + hd) * 2048 + t] = __float2bfloat16(acc[mf][nf][r]);
        }
      }
}

// ---------------- stage 2: flash attention (T12 swapped QK^T) ----------------
// 512 blocks x 512 threads (8 waves). Q-tile 256 rows (32/wave). KV tile 64.
// bh = bid&63, p = bid>>6 mapped so CU pairs (e,7-e) have equal totals.
// 3 LDS KV buffers, issue 2 ahead, counted vmcnt(2).
// Swapped QK^T: C = mfma(A=K, B=Q) -> lane owns one q (col=lr), 16 k's.
// A-row permutation f(a,i) = (i>>2)*8 + (a&1)*4 + (i&3) + (a>>1)*32 makes
// lane lk's C regs = exactly k = {lk*8..+7} (+32) -> PV B-frag is built
// IN-LANE (no LDS P, no cross-lane moves). Softmax: 2 shfl per q-group
// (max only); l-sum deferred per-lane to epilogue. O comes out transposed
// -> LDS transpose epilogue (bank-XOR'd) -> coalesced 16B Y stores.
// LDS swizzle F(r) = (r&7) ^ (2*(r>>3) & 7) keeps kb/vb reads uniform.
__global__ __launch_bounds__(512) void k_attn(
    const __hip_bfloat16* __restrict__ Q, const __hip_bfloat16* __restrict__ K,
    const __hip_bfloat16* __restrict__ VT, __hip_bfloat16* __restrict__ Y) {
  __shared__ __align__(16) char smem[49152];   // K bufs 0..2 | V bufs 0..2
  char* smc = smem;
  const int tid = threadIdx.x, lane = tid & 63, wid = tid >> 6;
  const int lr = lane & 15, lk = lane >> 4;

  const int bid = blockIdx.x;
  const int bh = bid & 63;
  const int p = bid >> 6;            // 0..7
  const int e = p & 3;
  const int x = (p < 4) ? p : 7 - e; // CU gets {e, 7-e}: 36 tiles total
  const int q0 = x * 256;
  const int qb = q0 + wid * 32;
  const size_t base = (size_t)bh * 2048 * 64;

  // staging: 512 chunks of 16B per 64x64 tile, source pre-swizzled by F
  const int srow = tid >> 3;                        // 0..63
  const int fs = (srow & 7) ^ ((2 * (srow >> 3)) & 7);
  const int scol = ((tid & 7) ^ fs) * 8;
  const __hip_bfloat16* kg = K + base + scol;
  const __hip_bfloat16* vg = VT + base + (size_t)srow * 2048 + scol;
  const int ldst = (tid & ~63) * 16;                // wave-uniform LDS dest

  // per-lane read offsets (bytes within an 8KB buffer)
  int koff[4][2], voff[4][2], kla[4];
#pragma unroll
  for (int a = 0; a < 4; a++) {
    const int ra = (lr >> 2) * 8 + (a & 1) * 4 + (lr & 3) + (a >> 1) * 32;
    const int fr = (ra & 7) ^ ((2 * (ra >> 3)) & 7);
    kla[a] = lk * 8 + (a & 1) * 4 + (a >> 1) * 32;
#pragma unroll
    for (int ks = 0; ks < 2; ks++)
      koff[a][ks] = ra * 128 + (((ks * 4 + lk) ^ fr) * 16);
  }
#pragma unroll
  for (int df = 0; df < 4; df++) {
    const int rv = df * 16 + lr;
    const int fv = (rv & 7) ^ ((2 * (rv >> 3)) & 7);
#pragma unroll
    for (int ks = 0; ks < 2; ks++)
      voff[df][ks] = rv * 128 + (((ks * 4 + lk) ^ fv) * 16);
  }

  short8 qf[2][2];
#pragma unroll
  for (int qg = 0; qg < 2; qg++)
#pragma unroll
    for (int ks = 0; ks < 2; ks++)
      qf[qg][ks] = *(const short8*)(Q + base + (size_t)(qb + qg * 16 + lr) * 64 + ks * 32 + lk * 8);

  const f32x4 fzero = {0.f, 0.f, 0.f, 0.f};
  f32x4 ot[2][4];                     // O^T accum: row d, col q
  float mrow[2] = {-1e30f, -1e30f}, lrow[2] = {0.f, 0.f};
#pragma unroll
  for (int qg = 0; qg < 2; qg++)
#pragma unroll
    for (int df = 0; df < 4; df++) ot[qg][df] = fzero;

  const int nkv = x * 4 + 4;
  // prologue: stage tiles 0,1 into bufs 0,1
  gload_lds16(kg + (size_t)srow * 64, (void*)(smc + ldst));
  gload_lds16(vg, (void*)(smc + 24576 + ldst));
  gload_lds16(kg + (size_t)(64 + srow) * 64, (void*)(smc + 8192 + ldst));
  gload_lds16(vg + 64, (void*)(smc + 24576 + 8192 + ldst));

  int cur = 0;
  for (int kt = 0; kt < nkv; ++kt) {
    const int k0 = kt * 64;
    if (kt + 1 < nkv) { asm volatile("s_waitcnt vmcnt(2)" ::: "memory"); }
    else              { asm volatile("s_waitcnt vmcnt(0)" ::: "memory"); }
    __builtin_amdgcn_s_barrier();
    __builtin_amdgcn_sched_barrier(0);

    if (k0 <= qb + 31) {   // wave-uniform: skip fully-masked tiles
      const char* kbuf = smc + cur * 8192;
      const char* vbuf = smc + 24576 + cur * 8192;

      f32x4 s[2][4];
#pragma unroll
      for (int qg = 0; qg < 2; qg++)
#pragma unroll
        for (int a = 0; a < 4; a++) s[qg][a] = fzero;

      __builtin_amdgcn_s_setprio(1);
#pragma unroll
      for (int ks = 0; ks < 2; ks++)
#pragma unroll
        for (int a = 0; a < 4; a++) {
          const short8 kb = *(const short8*)(kbuf + koff[a][ks]);
          s[0][a] = __builtin_amdgcn_mfma_f32_16x16x32_bf16(kb, qf[0][ks], s[0][a], 0, 0, 0);
          s[1][a] = __builtin_amdgcn_mfma_f32_16x16x32_bf16(kb, qf[1][ks], s[1][a], 0, 0, 0);
        }
      __builtin_amdgcn_s_setprio(0);

      const bool needmask = (k0 + 63 > qb);
      short8 pb[2][2];

#pragma unroll
      for (int qg = 0; qg < 2; qg++) {
        const int qq = qb + qg * 16 + lr;
        if (needmask) {
#pragma unroll
          for (int a = 0; a < 4; a++)
#pragma unroll
            for (int r = 0; r < 4; r++)
              if (k0 + kla[a] + r > qq) s[qg][a][r] = -1e30f;
        }
        // in-lane max over 16, then 2 shfl across lk groups
        f32x4 m4;
#pragma unroll
        for (int r = 0; r < 4; r++)
          m4[r] = fmaxf(fmaxf(s[qg][0][r], s[qg][1][r]), fmaxf(s[qg][2][r], s[qg][3][r]));
        float mx = fmaxf(fmaxf(m4[0], m4[1]), fmaxf(m4[2], m4[3]));
        mx = fmaxf(mx, __shfl_xor(mx, 16, 64));
        mx = fmaxf(mx, __shfl_xor(mx, 32, 64));
        const float mold = mrow[qg];
        float m;
        if (__all(mx - mold <= 8.f)) {
          m = mold;            // T13 defer: P bounded by 2^8
        } else {
          m = fmaxf(mold, mx);
          const float alpha = EXP2(mold - m);
          lrow[qg] *= alpha;
          mrow[qg] = m;
#pragma unroll
          for (int df = 0; df < 4; df++) ot[qg][df] *= alpha;
        }
        float rs = 0.f;
#pragma unroll
        for (int a = 0; a < 4; a++)
#pragma unroll
          for (int r = 0; r < 4; r++) {
            const float pv = EXP2(s[qg][a][r] - m);
            s[qg][a][r] = pv;
            rs += pv;
          }
        lrow[qg] += rs;        // per-lane partial; cross-lane at epilogue
        // pack PV B-frags: e<4 from block 2ksP, e>=4 from 2ksP+1 (in-lane!)
#pragma unroll
        for (int ksP = 0; ksP < 2; ksP++) {
          short8 w;
#pragma unroll
          for (int ee = 0; ee < 4; ee++) {
            __hip_bfloat16 h0 = __float2bfloat16(s[qg][2 * ksP][ee]);
            __hip_bfloat16 h1 = __float2bfloat16(s[qg][2 * ksP + 1][ee]);
            w[ee] = *(short*)&h0;
            w[4 + ee] = *(short*)&h1;
          }
          pb[qg][ksP] = w;
        }
      }

      // PV: o^T[d][q] += V^T[d][k] * P[k][q]
      __builtin_amdgcn_s_setprio(1);
#pragma unroll
      for (int ks = 0; ks < 2; ks++)
#pragma unroll
        for (int df = 0; df < 4; df++) {
          const short8 vb = *(const short8*)(vbuf + voff[df][ks]);
          ot[0][df] = __builtin_amdgcn_mfma_f32_16x16x32_bf16(vb, pb[0][ks], ot[0][df], 0, 0, 0);
          ot[1][df] = __builtin_amdgcn_mfma_f32_16x16x32_bf16(vb, pb[1][ks], ot[1][df], 0, 0, 0);
        }
      __builtin_amdgcn_s_setprio(0);
    }

    // issue tile kt+2 into buf (cur+2)%3 AFTER compute (3-buf race-freedom)
    if (kt + 2 < nkv) {
      const int kn = (kt + 2) * 64;
      int tb = cur + 2; if (tb >= 3) tb -= 3;
      gload_lds16(kg + (size_t)(kn + srow) * 64, (void*)(smc + tb * 8192 + ldst));
      gload_lds16(vg + kn, (void*)(smc + 24576 + tb * 8192 + ldst));
    }
    cur = (cur + 1 == 3) ? 0 : cur + 1;
  }

  // ---- epilogue: normalize, transpose through LDS, coalesced store ----
  __syncthreads();                      // all waves done with K/V buffers
  unsigned int* Os = (unsigned int*)smc; // 256 rows x 32 u32 = 32 KB
#pragma unroll
  for (int qg = 0; qg < 2; qg++) {
    float ls = lrow[qg];
    ls += __shfl_xor(ls, 16, 64);
    ls += __shfl_xor(ls, 32, 64);
    const float inv = 1.f / ls;
    const int qlocal = wid * 32 + qg * 16 + lr;
    const int sw = (lr & 7) << 2;
#pragma unroll
    for (int df = 0; df < 4; df++)
#pragma unroll
      for (int e2 = 0; e2 < 2; e2++) {
        __hip_bfloat16 h0 = __float2bfloat16(ot[qg][df][2 * e2] * inv);
        __hip_bfloat16 h1 = __float2bfloat16(ot[qg][df][2 * e2 + 1] * inv);
        const unsigned int w = (unsigned int)*(unsigned short*)&h0 |
                               ((unsigned int)*(unsigned short*)&h1 << 16);
        Os[qlocal * 32 + ((df * 8 + lk * 2 + e2) ^ sw)] = w;
      }
  }
  __syncthreads();
  {
    const int qrow = tid >> 1, half = tid & 1, q7 = qrow & 7;
    const int b = bh >> 4, h = bh & 15;
    unsigned int* Yu = (unsigned int*)Y;
    const size_t rowbase = ((size_t)b * 2048 + q0 + qrow) * 512 + h * 32;
#pragma unroll
    for (int g = 0; g < 4; g++) {
      const int cg = half * 4 + g;
      const u32x4 v = *(const u32x4*)(smc + qrow * 128 + ((cg ^ q7) * 16));
      *(u32x4*)(Yu + rowbase + cg * 4) = v;
    }
  }
}

// ---------------- stage 3: output GEMM (8 waves, 3-buf counted vmcnt) ----------------
__global__ __launch_bounds__(512) void k_gemm_out(
    const __hip_bfloat16* __restrict__ X, const __hip_bfloat16* __restrict__ W,
    void* __restrict__ out, const int* __restrict__ flag) {
  __shared__ __align__(16) __hip_bfloat16 As[3][128 * 32];
  __shared__ __align__(16) __hip_bfloat16 Bs[3][128 * 32];
  const int tid = threadIdx.x;
  const int lane = tid & 63;
  const int wid = tid >> 6;
  const int wr = wid & 3, wc = wid >> 2;
  const int lr = lane & 15, lk = lane >> 4;
  const int m0 = blockIdx.x * 128;
  const int n0 = blockIdx.y * 128;
  const int sw = (lr >> 1) & 3;

  const int row = tid >> 2;
  const int ce = ((tid & 3) ^ ((row >> 1) & 3)) * 8;
  const int dst = (tid & ~63) * 8;

  const f32x4 fzero = {0.f, 0.f, 0.f, 0.f};
  f32x4 acc[2][4];
#pragma unroll
  for (int i = 0; i < 2; i++)
#pragma unroll
    for (int j = 0; j < 4; j++) acc[i][j] = fzero;

#define OUT_STAGE(buf, kt2)                                                        \
  {                                                                                \
    const int kk = (kt2) * 32;                                                     \
    gload_lds16(X + (size_t)(m0 + row) * 1024 + kk + ce, (void*)(As[buf] + dst));  \
    gload_lds16(W + (size_t)(n0 + row) * 1024 + kk + ce, (void*)(Bs[buf] + dst));  \
  }

  OUT_STAGE(0, 0)
  OUT_STAGE(1, 1)

  int cur = 0;
  for (int kt = 0; kt < 32; ++kt) {
    if (kt + 1 < 32) { asm volatile("s_waitcnt vmcnt(2)" ::: "memory"); }
    else             { asm volatile("s_waitcnt vmcnt(0)" ::: "memory"); }
    __builtin_amdgcn_s_barrier();
    __builtin_amdgcn_sched_barrier(0);

    short8 a[2], b[4];
#pragma unroll
    for (int i = 0; i < 2; i++) a[i] = *(const short8*)(As[cur] + (wr * 32 + i * 16 + lr) * 32 + ((lk ^ sw) * 8));
#pragma unroll
    for (int i = 0; i < 4; i++) b[i] = *(const short8*)(Bs[cur] + (wc * 64 + i * 16 + lr) * 32 + ((lk ^ sw) * 8));
#pragma unroll
    for (int mf = 0; mf < 2; mf++)
#pragma unroll
      for (int nf = 0; nf < 4; nf++)
        acc[mf][nf] = __builtin_amdgcn_mfma_f32_16x16x32_bf16(a[mf], b[nf], acc[mf][nf], 0, 0, 0);

    if (kt + 2 < 32) {
      int tb = cur + 2; if (tb >= 3) tb -= 3;
      OUT_STAGE(tb, kt + 2)
    }
    cur = (cur + 1 == 3) ? 0 : cur + 1;
  }
#undef OUT_STAGE

  const int f = *flag;
#pragma unroll
  for (int mf = 0; mf < 2; mf++)
#pragma unroll
    for (int nf = 0; nf < 4; nf++)
#pragma unroll
      for (int r = 0; r < 4; r++) {
        const int orow = m0 + wr * 32 + mf * 16 + lk * 4 + r;
        const int col = n0 + wc * 64 + nf * 16 + lr;
        const size_t oi = (size_t)orow * 1024 + col;
        if (f) ((__hip_bfloat16*)out)[oi] = __float2bfloat16(acc[mf][nf][r]);
        else   ((float*)out)[oi] = acc[mf][nf][r];
      }
}

// ---------------- launch ----------------
extern "C" void kernel_launch(void* const* d_in, const int* in_sizes, int n_in,
                              void* d_out, int out_size, void* d_ws, size_t ws_size,
                              hipStream_t stream) {
  const void* x = d_in[0];     // [4,2048,1024]
  const void* wqkv = d_in[1];  // [3072,1024]
  const void* wo = d_in[2];    // [1024,1024]

  char* ws = (char*)d_ws;
  int* flag = (int*)ws;
  __hip_bfloat16* xb    = (__hip_bfloat16*)(ws + 256);
  __hip_bfloat16* wqkvb = xb + 8388608;
  __hip_bfloat16* wob   = wqkvb + 3145728;
  __hip_bfloat16* qws   = wob + 1048576;
  __hip_bfloat16* kws   = qws + 8388608;   // 64*2048*64
  __hip_bfloat16* vtws  = kws + 8388608;
  __hip_bfloat16* yws   = xb;              // alias: xb dead after QKV GEMM
  // peak ws use: ~72 MB

  k_detect<<<1, 256, 0, stream>>>((const unsigned int*)x, flag);
  k_convert3<<<2048, 256, 0, stream>>>(x, wqkv, wo, (unsigned short*)xb, flag);

  dim3 g1(64, 12);
  k_gemm_qkv<<<g1, 512, 0, stream>>>(xb, wqkvb, qws, kws, vtws);

  k_attn<<<512, 512, 0, stream>>>(qws, kws, vtws, yws);

  dim3 g3(64, 8);
  k_gemm_out<<<g3, 512, 0, stream>>>(yws, wob, d_out, flag);
}